// Round 16
// baseline (193.839 us; speedup 1.0000x reference)
//
#include <hip/hip_runtime.h>

#define NB  32
#define IDF 768
#define SLN 128
#define QLN 1024
#define NT  24   // IDF/32 k-tiles (even)

typedef __bf16 v8bf __attribute__((ext_vector_type(8)));
typedef __bf16 v4bf __attribute__((ext_vector_type(4)));
typedef float  v4f  __attribute__((ext_vector_type(4)));

#define MFMA16 __builtin_amdgcn_mfma_f32_16x16x32_bf16

__device__ __forceinline__ void split2(float x, __bf16& h, __bf16& l) {
  h = (__bf16)x;
  l = (__bf16)(x - (float)h);
}

__device__ __forceinline__ void gload16(const void* g, void* l) {
  __builtin_amdgcn_global_load_lds(
      (const __attribute__((address_space(1))) void*)g,
      (__attribute__((address_space(3))) void*)l, 16, 0, 0);
}

__device__ __forceinline__ void lbar() {
  asm volatile("s_waitcnt lgkmcnt(0)" ::: "memory");
  __builtin_amdgcn_sched_barrier(0);
  __builtin_amdgcn_s_barrier();
  __builtin_amdgcn_sched_barrier(0);
}

// -----------------------------------------------------------------------------
// K0 prep: blocks 0..575 split W -> Wh/Wl; blocks 576..959 transpose+split ctx.
// -----------------------------------------------------------------------------
__global__ __launch_bounds__(256) void prep_k(const float* __restrict__ W,
                                              const float* __restrict__ ctx,
                                              __bf16* __restrict__ Wh,
                                              __bf16* __restrict__ Wl,
                                              __bf16* __restrict__ cTh,
                                              __bf16* __restrict__ cTl) {
  const int bid = blockIdx.x, t = threadIdx.x;
  __shared__ float tl[64][133];
  if (bid < 576) {
    int idx = bid * 1024 + t * 4;
    float4 v = *(const float4*)(W + idx);
    float vals[4] = {v.x, v.y, v.z, v.w};
    v4bf h, l;
#pragma unroll
    for (int e = 0; e < 4; ++e) {
      __bf16 hh, ll;
      split2(vals[e], hh, ll);
      h[e] = hh;
      l[e] = ll;
    }
    *(v4bf*)(Wh + idx) = h;
    *(v4bf*)(Wl + idx) = l;
    return;
  }
  const int cid = bid - 576;
  const int b = cid / 12, c0 = (cid % 12) * 64;
#pragma unroll
  for (int j = 0; j < 8; ++j) {
    int u = j * 256 + t;
    int c = u >> 5, s4 = (u & 31) * 4;
    *(float4*)&tl[c][s4] =
        *(const float4*)(ctx + ((size_t)b * IDF + c0 + c) * SLN + s4);
  }
  __syncthreads();
#pragma unroll
  for (int j = 0; j < 8; ++j) {
    int u = j * 256 + t;
    int s = u >> 4, c4 = (u & 15) * 4;
    v4bf h, l;
#pragma unroll
    for (int e = 0; e < 4; ++e) {
      __bf16 hh, ll;
      split2(tl[c4 + e][s], hh, ll);
      h[e] = hh;
      l[e] = ll;
    }
    *(v4bf*)(cTh + ((size_t)b * SLN + s) * IDF + c0 + c4) = h;
    *(v4bf*)(cTl + ((size_t)b * SLN + s) * IDF + c0 + c4) = l;
  }
}

// -----------------------------------------------------------------------------
// K1 proj: unchanged (known-good).
// -----------------------------------------------------------------------------
__global__ __launch_bounds__(256) void proj_k(const __bf16* __restrict__ cTh,
                                              const __bf16* __restrict__ cTl,
                                              const __bf16* __restrict__ Wh,
                                              const __bf16* __restrict__ Wl,
                                              __bf16* __restrict__ STh,
                                              __bf16* __restrict__ STl,
                                              __bf16* __restrict__ Shv) {
  const int b = blockIdx.y, o0 = blockIdx.x * 32;
  const int t = threadIdx.x, w = t >> 6, lane = t & 63;
  const int lr = lane & 15, lg = lane >> 4;
  const int ws = w >> 1, wq = w & 1;
  __shared__ __bf16 AhL[128][32];
  __shared__ __bf16 AlL[128][32];

  v4f acc[4];
#pragma unroll
  for (int fr = 0; fr < 4; ++fr) acc[fr] = (v4f){0.f, 0.f, 0.f, 0.f};

  const int ra = t >> 1, ca0 = (t & 1) * 2;
  const int swA = (ra >> 1) & 3;
  const int pa0 = (ca0 ^ swA) * 8, pa1 = ((ca0 + 1) ^ swA) * 8;
  const __bf16* pAh = cTh + ((size_t)b * SLN + ra) * IDF + ca0 * 8;
  const __bf16* pAl = cTl + ((size_t)b * SLN + ra) * IDF + ca0 * 8;
  const size_t wOff = (size_t)(o0 + wq * 16 + lr) * IDF + lg * 8;

  uint4 aAh0, aAh1, aAl0, aAl1;
  uint4 bAh0, bAh1, bAl0, bAl1;
  v8bf bhc, blc, bhn, bln;
  aAh0 = *(const uint4*)(pAh);
  aAh1 = *(const uint4*)(pAh + 8);
  aAl0 = *(const uint4*)(pAl);
  aAl1 = *(const uint4*)(pAl + 8);
  bAh0 = *(const uint4*)(pAh + 32);
  bAh1 = *(const uint4*)(pAh + 40);
  bAl0 = *(const uint4*)(pAl + 32);
  bAl1 = *(const uint4*)(pAl + 40);
  bhc = *(const v8bf*)(Wh + wOff);
  blc = *(const v8bf*)(Wl + wOff);

#define PROJ_BODY(S0, S1, S2, S3, IT)                                          \
  {                                                                            \
    lbar();                                                                    \
    *(uint4*)&AhL[ra][pa0] = S0;                                               \
    *(uint4*)&AhL[ra][pa1] = S1;                                               \
    *(uint4*)&AlL[ra][pa0] = S2;                                               \
    *(uint4*)&AlL[ra][pa1] = S3;                                               \
    if ((IT) + 2 < NT) {                                                       \
      S0 = *(const uint4*)(pAh + ((IT) + 2) * 32);                             \
      S1 = *(const uint4*)(pAh + ((IT) + 2) * 32 + 8);                         \
      S2 = *(const uint4*)(pAl + ((IT) + 2) * 32);                             \
      S3 = *(const uint4*)(pAl + ((IT) + 2) * 32 + 8);                         \
    }                                                                          \
    if ((IT) + 1 < NT) {                                                       \
      bhn = *(const v8bf*)(Wh + wOff + ((IT) + 1) * 32);                       \
      bln = *(const v8bf*)(Wl + wOff + ((IT) + 1) * 32);                       \
    }                                                                          \
    lbar();                                                                    \
    _Pragma("unroll") for (int fr = 0; fr < 4; ++fr) {                         \
      const int r = ws * 64 + fr * 16 + lr;                                    \
      const int pp = (lg ^ ((r >> 1) & 3)) * 8;                                \
      v8bf ah = *(const v8bf*)&AhL[r][pp];                                     \
      v8bf al = *(const v8bf*)&AlL[r][pp];                                     \
      acc[fr] = MFMA16(ah, bhc, acc[fr], 0, 0, 0);                             \
      acc[fr] = MFMA16(ah, blc, acc[fr], 0, 0, 0);                             \
      acc[fr] = MFMA16(al, bhc, acc[fr], 0, 0, 0);                             \
    }                                                                          \
    bhc = bhn;                                                                 \
    blc = bln;                                                                 \
  }

  for (int it2 = 0; it2 < NT / 2; ++it2) {
    const int itE = it2 * 2;
    PROJ_BODY(aAh0, aAh1, aAl0, aAl1, itE);
    PROJ_BODY(bAh0, bAh1, bAl0, bAl1, itE + 1);
  }
#undef PROJ_BODY

  const int o = o0 + wq * 16 + lr;
#pragma unroll
  for (int fr = 0; fr < 4; ++fr) {
    __bf16 hp[4];
#pragma unroll
    for (int r = 0; r < 4; ++r) {
      int s = ws * 64 + fr * 16 + lg * 4 + r;
      __bf16 h, l;
      split2(acc[fr][r], h, l);
      STh[((size_t)b * SLN + s) * IDF + o] = h;
      STl[((size_t)b * SLN + s) * IDF + o] = l;
      hp[r] = h;
    }
    *(v4bf*)(Shv + ((size_t)b * IDF + o) * SLN + ws * 64 + fr * 16 + lg * 4) =
        (v4bf){hp[0], hp[1], hp[2], hp[3]};
  }
}

// -----------------------------------------------------------------------------
// DIAG kernels (write NOTHING; timing-only, read via rocprof next round).
// MODE 1: full QK loop (gload+vmcnt+barrier+split+MFMA), acc sunk via asm.
// MODE 2: staging skeleton only (gload+vmcnt+barrier).
// Grid 1024 = 2x the real 512 config (each (b,q0) run twice) so these rank
// ABOVE qkpv in the top-5-by-duration table. Divide shown dur by 2.
// -----------------------------------------------------------------------------
template <int MODE>
__global__ __launch_bounds__(512, 4) void qkdiag(const float* __restrict__ input,
                                                 const __bf16* __restrict__ STh,
                                                 const __bf16* __restrict__ STl) {
  const int bid = blockIdx.x & 511;
  const int nid = (bid & 7) * 64 + (bid >> 3);
  const int b = nid >> 4, q0 = (nid & 15) * 64;
  const int t = threadIdx.x, w = t >> 6, lane = t & 63;
  const int lr = lane & 15, lg = lane >> 4;
  const int wq = w & 3, sh = w >> 2;

  __shared__ __align__(16) char lds[50688];

  v4f acc[4];
#pragma unroll
  for (int fr = 0; fr < 4; ++fr) acc[fr] = (v4f){0.f, 0.f, 0.f, 0.f};

  const int raA = w * 16 + (lane >> 2);
  const int cA  = (lane & 3) ^ ((raA >> 1) & 3);
  const __bf16* gAh = STh + ((size_t)b * SLN + raA) * IDF + cA * 8;
  const __bf16* gAl = STl + ((size_t)b * SLN + raA) * IDF + cA * 8;
  const int rT = w * 4 + (lane >> 4);
  const int cT = (((lane & 15) * 4) - (((w >> 1) & 1) << 4)) & 63;
  const float* gTi = input + ((size_t)b * IDF + rT) * QLN + q0 + cT;
  const int wavB = w * 1024;
  const int colTi = (wq * 16 + lr + ((lg & 1) << 4)) & 63;

  gload16(gAh, lds + wavB);
  gload16(gAl, lds + 8192 + wavB);
  gload16(gTi, lds + 16384 + wavB);
  gload16(gAh + 32, lds + 24576 + wavB);
  gload16(gAl + 32, lds + 24576 + 8192 + wavB);
  gload16(gTi + (size_t)32 * QLN, lds + 24576 + 16384 + wavB);

#define QK_DITER(CUROFF, IT, VMC)                                              \
  {                                                                            \
    asm volatile("s_waitcnt vmcnt(" #VMC ")" ::: "memory");                    \
    __builtin_amdgcn_s_barrier();                                              \
    if (MODE == 1) {                                                           \
      const float* Tb = (const float*)(lds + (CUROFF) + 16384);                \
      v8bf bh, bl;                                                             \
      _Pragma("unroll") for (int e = 0; e < 8; ++e) {                          \
        __bf16 h, l;                                                           \
        split2(Tb[(lg * 8 + e) * 64 + colTi], h, l);                           \
        bh[e] = h;                                                             \
        bl[e] = l;                                                             \
      }                                                                        \
      const __bf16* Ab = (const __bf16*)(lds + (CUROFF));                      \
      __builtin_amdgcn_s_setprio(1);                                           \
      _Pragma("unroll") for (int fr = 0; fr < 4; ++fr) {                       \
        const int r = sh * 64 + fr * 16 + lr;                                  \
        const int pp = (lg ^ ((r >> 1) & 3)) * 8;                              \
        v8bf ah = *(const v8bf*)(Ab + r * 32 + pp);                            \
        v8bf al = *(const v8bf*)(Ab + 4096 + r * 32 + pp);                     \
        acc[fr] = MFMA16(ah, bh, acc[fr], 0, 0, 0);                            \
        acc[fr] = MFMA16(ah, bl, acc[fr], 0, 0, 0);                            \
        acc[fr] = MFMA16(al, bh, acc[fr], 0, 0, 0);                            \
      }                                                                        \
      __builtin_amdgcn_s_setprio(0);                                           \
      asm volatile("s_waitcnt lgkmcnt(0)" ::: "memory");                       \
    }                                                                          \
    __builtin_amdgcn_s_barrier();                                              \
    if ((IT) + 2 < NT) {                                                       \
      gload16(gAh + (size_t)((IT) + 2) * 32, lds + (CUROFF) + wavB);           \
      gload16(gAl + (size_t)((IT) + 2) * 32, lds + (CUROFF) + 8192 + wavB);    \
      gload16(gTi + (size_t)((IT) + 2) * 32 * QLN,                             \
              lds + (CUROFF) + 16384 + wavB);                                  \
    }                                                                          \
  }

  for (int it2 = 0; it2 < 11; ++it2) {
    const int itE = it2 * 2;
    QK_DITER(0, itE, 3);
    QK_DITER(24576, itE + 1, 3);
  }
  QK_DITER(0, 22, 3);
  QK_DITER(24576, 23, 0);
#undef QK_DITER

  if (MODE == 1) {
#pragma unroll
    for (int fr = 0; fr < 4; ++fr)
      asm volatile("" ::"v"(acc[fr][0]), "v"(acc[fr][1]), "v"(acc[fr][2]),
                   "v"(acc[fr][3]));
  }
}

// -----------------------------------------------------------------------------
// K2 qkpv: EXACT round-14 kernel (passing, 100 us).
// -----------------------------------------------------------------------------
__global__ __launch_bounds__(512, 4) void qkpv_k(const float* __restrict__ input,
                                                 const __bf16* __restrict__ STh,
                                                 const __bf16* __restrict__ STl,
                                                 const __bf16* __restrict__ Shv,
                                                 const int* __restrict__ mask,
                                                 float* __restrict__ wc,
                                                 float* __restrict__ attn_out) {
  const int bid = blockIdx.x;
  const int nid = (bid & 7) * 64 + (bid >> 3);
  const int b = nid >> 4, q0 = (nid & 15) * 64;
  const int t = threadIdx.x, w = t >> 6, lane = t & 63;
  const int lr = lane & 15, lg = lane >> 4;
  const int wq = w & 3, sh = w >> 2;

  __shared__ __align__(16) char lds[50688];
  float* const msk  = (float*)(lds + 49152);
  float* const redm = (float*)(lds + 49664);
  float* const reds = (float*)(lds + 50176);
  char* const PLb = lds;

  if (t < SLN) msk[t] = -10000.0f * (float)mask[b * SLN + t];

  v4f acc[4];
#pragma unroll
  for (int fr = 0; fr < 4; ++fr) acc[fr] = (v4f){0.f, 0.f, 0.f, 0.f};

  const int raA = w * 16 + (lane >> 2);
  const int cA  = (lane & 3) ^ ((raA >> 1) & 3);
  const __bf16* gAh = STh + ((size_t)b * SLN + raA) * IDF + cA * 8;
  const __bf16* gAl = STl + ((size_t)b * SLN + raA) * IDF + cA * 8;
  const int rT = w * 4 + (lane >> 4);
  const int cT = (((lane & 15) * 4) - (((w >> 1) & 1) << 4)) & 63;
  const float* gTi = input + ((size_t)b * IDF + rT) * QLN + q0 + cT;
  const int wavB = w * 1024;
  const int colTi = (wq * 16 + lr + ((lg & 1) << 4)) & 63;

  gload16(gAh, lds + wavB);
  gload16(gAl, lds + 8192 + wavB);
  gload16(gTi, lds + 16384 + wavB);
  gload16(gAh + 32, lds + 24576 + wavB);
  gload16(gAl + 32, lds + 24576 + 8192 + wavB);
  gload16(gTi + (size_t)32 * QLN, lds + 24576 + 16384 + wavB);

#define QK_ITER(CUROFF, IT, VMC)                                               \
  {                                                                            \
    asm volatile("s_waitcnt vmcnt(" #VMC ")" ::: "memory");                    \
    __builtin_amdgcn_s_barrier();                                              \
    const float* Tb = (const float*)(lds + (CUROFF) + 16384);                  \
    v8bf bh, bl;                                                               \
    _Pragma("unroll") for (int e = 0; e < 8; ++e) {                            \
      __bf16 h, l;                                                             \
      split2(Tb[(lg * 8 + e) * 64 + colTi], h, l);                             \
      bh[e] = h;                                                               \
      bl[e] = l;                                                               \
    }                                                                          \
    const __bf16* Ab = (const __bf16*)(lds + (CUROFF));                        \
    __builtin_amdgcn_s_setprio(1);                                             \
    _Pragma("unroll") for (int fr = 0; fr < 4; ++fr) {                         \
      const int r = sh * 64 + fr * 16 + lr;                                    \
      const int pp = (lg ^ ((r >> 1) & 3)) * 8;                                \
      v8bf ah = *(const v8bf*)(Ab + r * 32 + pp);                              \
      v8bf al = *(const v8bf*)(Ab + 4096 + r * 32 + pp);                       \
      acc[fr] = MFMA16(ah, bh, acc[fr], 0, 0, 0);                              \
      acc[fr] = MFMA16(ah, bl, acc[fr], 0, 0, 0);                              \
      acc[fr] = MFMA16(al, bh, acc[fr], 0, 0, 0);                              \
    }                                                                          \
    __builtin_amdgcn_s_setprio(0);                                             \
    asm volatile("s_waitcnt lgkmcnt(0)" ::: "memory");                         \
    __builtin_amdgcn_s_barrier();                                              \
    if ((IT) + 2 < NT) {                                                       \
      gload16(gAh + (size_t)((IT) + 2) * 32, lds + (CUROFF) + wavB);           \
      gload16(gAl + (size_t)((IT) + 2) * 32, lds + (CUROFF) + 8192 + wavB);    \
      gload16(gTi + (size_t)((IT) + 2) * 32 * QLN,                             \
              lds + (CUROFF) + 16384 + wavB);                                  \
    }                                                                          \
  }

  for (int it2 = 0; it2 < 11; ++it2) {
    const int itE = it2 * 2;
    QK_ITER(0, itE, 3);
    QK_ITER(24576, itE + 1, 3);
  }
  QK_ITER(0, 22, 3);
  QK_ITER(24576, 23, 0);
#undef QK_ITER

  const int q = q0 + wq * 16 + lr;
  float mx = -3.0e38f;
#pragma unroll
  for (int fr = 0; fr < 4; ++fr)
#pragma unroll
    for (int r = 0; r < 4; ++r) {
      acc[fr][r] += msk[sh * 64 + fr * 16 + lg * 4 + r];
      mx = fmaxf(mx, acc[fr][r]);
    }
  mx = fmaxf(mx, __shfl_xor(mx, 16));
  mx = fmaxf(mx, __shfl_xor(mx, 32));
  if (lg == 0) redm[sh * 64 + wq * 16 + lr] = mx;
  __syncthreads();
  mx = fmaxf(redm[wq * 16 + lr], redm[64 + wq * 16 + lr]);
  float sum = 0.f;
#pragma unroll
  for (int fr = 0; fr < 4; ++fr)
#pragma unroll
    for (int r = 0; r < 4; ++r) {
      float e = __expf(acc[fr][r] - mx);
      acc[fr][r] = e;
      sum += e;
    }
  sum += __shfl_xor(sum, 16);
  sum += __shfl_xor(sum, 32);
  if (lg == 0) reds[sh * 64 + wq * 16 + lr] = sum;
  __syncthreads();
  const float inv = 1.0f / (reds[wq * 16 + lr] + reds[64 + wq * 16 + lr]);
  const int qloc = wq * 16 + lr;
#pragma unroll
  for (int fr = 0; fr < 4; ++fr) {
    __bf16 hp[4];
#pragma unroll
    for (int r = 0; r < 4; ++r) {
      float p = acc[fr][r] * inv;
      attn_out[((size_t)b * SLN + sh * 64 + fr * 16 + lg * 4 + r) * QLN + q] = p;
      hp[r] = (__bf16)p;
    }
    const int g = (sh * 8 + fr * 2 + (lg >> 1)) ^ lr;
    *(v4bf*)(PLb + qloc * 256 + g * 16 + (lg & 1) * 8) =
        (v4bf){hp[0], hp[1], hp[2], hp[3]};
  }
  __syncthreads();

  const int qfp = (w & 1) * 2;
  const int islab = (w >> 1) * 192;
  v8bf pa0v[4], pa1v[4];
#pragma unroll
  for (int kt = 0; kt < 4; ++kt) {
    const int g0 = (kt * 4 + lg) ^ lr;
    pa0v[kt] = *(const v8bf*)(PLb + (qfp * 16 + lr) * 256 + g0 * 16);
    pa1v[kt] = *(const v8bf*)(PLb + ((qfp + 1) * 16 + lr) * 256 + g0 * 16);
  }
  const __bf16* pShv = Shv + ((size_t)b * IDF + islab + lr) * SLN + lg * 8;
  float* pWc = wc + ((size_t)b * IDF + islab + lr) * QLN + q0;
#pragma unroll 2
  for (int ifr = 0; ifr < 12; ++ifr) {
    v4f a0 = (v4f){0.f, 0.f, 0.f, 0.f};
    v4f a1 = (v4f){0.f, 0.f, 0.f, 0.f};
#pragma unroll
    for (int kt = 0; kt < 4; ++kt) {
      v8bf bb = *(const v8bf*)(pShv + (size_t)(ifr * 16) * SLN + kt * 32);
      a0 = MFMA16(pa0v[kt], bb, a0, 0, 0, 0);
      a1 = MFMA16(pa1v[kt], bb, a1, 0, 0, 0);
    }
    *(float4*)(pWc + (size_t)(ifr * 16) * QLN + qfp * 16 + lg * 4) =
        make_float4(a0[0], a0[1], a0[2], a0[3]);
    *(float4*)(pWc + (size_t)(ifr * 16) * QLN + (qfp + 1) * 16 + lg * 4) =
        make_float4(a1[0], a1[1], a1[2], a1[3]);
  }
}

// -----------------------------------------------------------------------------
extern "C" void kernel_launch(void* const* d_in, const int* in_sizes, int n_in,
                              void* d_out, int out_size, void* d_ws, size_t ws_size,
                              hipStream_t stream) {
  const float* input   = (const float*)d_in[0];
  const float* context = (const float*)d_in[1];
  const int*   mask    = (const int*)d_in[2];
  const float* w_conv  = (const float*)d_in[3];

  float* out      = (float*)d_out;
  float* wc       = out;
  float* attn_out = out + (size_t)NB * IDF * QLN;

  const size_t SE = (size_t)NB * SLN * IDF;  // 3,145,728
  const size_t WE = (size_t)IDF * IDF;       // 589,824
  __bf16* wsb = (__bf16*)d_ws;
  __bf16* STh = wsb;
  __bf16* STl = STh + SE;
  __bf16* Shv = STl + SE;
  __bf16* scr = (__bf16*)wc;
  __bf16* cTh = scr;
  __bf16* cTl = cTh + SE;
  __bf16* Wh  = cTl + SE;
  __bf16* Wl  = Wh + WE;

  prep_k<<<960, 256, 0, stream>>>(w_conv, context, Wh, Wl, cTh, cTl);
  proj_k<<<dim3(24, NB), 256, 0, stream>>>(cTh, cTl, Wh, Wl, STh, STl, Shv);
  // Diagnostics (write nothing; 2x grid so they rank above qkpv in top-5):
  qkdiag<1><<<1024, 512, 0, stream>>>(input, STh, STl);  // full QK loop
  qkdiag<2><<<1024, 512, 0, stream>>>(input, STh, STl);  // staging skeleton
  qkpv_k<<<512, 512, 0, stream>>>(input, STh, STl, Shv, mask, wc, attn_out);
}

// Round 17
// 124.814 us; speedup vs baseline: 1.5530x; 1.5530x over previous
//
#include <hip/hip_runtime.h>

#define NB  32
#define IDF 768
#define SLN 128
#define QLN 1024
#define NT  24   // IDF/32 k-tiles (even)

typedef __bf16 v8bf __attribute__((ext_vector_type(8)));
typedef __bf16 v4bf __attribute__((ext_vector_type(4)));
typedef float  v4f  __attribute__((ext_vector_type(4)));

#define MFMA16 __builtin_amdgcn_mfma_f32_16x16x32_bf16

__device__ __forceinline__ void split2(float x, __bf16& h, __bf16& l) {
  h = (__bf16)x;
  l = (__bf16)(x - (float)h);
}

__device__ __forceinline__ void gload16(const void* g, void* l) {
  __builtin_amdgcn_global_load_lds(
      (const __attribute__((address_space(1))) void*)g,
      (__attribute__((address_space(3))) void*)l, 16, 0, 0);
}

__device__ __forceinline__ void lbar() {
  asm volatile("s_waitcnt lgkmcnt(0)" ::: "memory");
  __builtin_amdgcn_sched_barrier(0);
  __builtin_amdgcn_s_barrier();
  __builtin_amdgcn_sched_barrier(0);
}

// -----------------------------------------------------------------------------
// K0 prep: blocks 0..575 split W -> Wh/Wl; blocks 576..959 transpose+split ctx.
// -----------------------------------------------------------------------------
__global__ __launch_bounds__(256) void prep_k(const float* __restrict__ W,
                                              const float* __restrict__ ctx,
                                              __bf16* __restrict__ Wh,
                                              __bf16* __restrict__ Wl,
                                              __bf16* __restrict__ cTh,
                                              __bf16* __restrict__ cTl) {
  const int bid = blockIdx.x, t = threadIdx.x;
  __shared__ float tl[64][133];
  if (bid < 576) {
    int idx = bid * 1024 + t * 4;
    float4 v = *(const float4*)(W + idx);
    float vals[4] = {v.x, v.y, v.z, v.w};
    v4bf h, l;
#pragma unroll
    for (int e = 0; e < 4; ++e) {
      __bf16 hh, ll;
      split2(vals[e], hh, ll);
      h[e] = hh;
      l[e] = ll;
    }
    *(v4bf*)(Wh + idx) = h;
    *(v4bf*)(Wl + idx) = l;
    return;
  }
  const int cid = bid - 576;
  const int b = cid / 12, c0 = (cid % 12) * 64;
#pragma unroll
  for (int j = 0; j < 8; ++j) {
    int u = j * 256 + t;
    int c = u >> 5, s4 = (u & 31) * 4;
    *(float4*)&tl[c][s4] =
        *(const float4*)(ctx + ((size_t)b * IDF + c0 + c) * SLN + s4);
  }
  __syncthreads();
#pragma unroll
  for (int j = 0; j < 8; ++j) {
    int u = j * 256 + t;
    int s = u >> 4, c4 = (u & 15) * 4;
    v4bf h, l;
#pragma unroll
    for (int e = 0; e < 4; ++e) {
      __bf16 hh, ll;
      split2(tl[c4 + e][s], hh, ll);
      h[e] = hh;
      l[e] = ll;
    }
    *(v4bf*)(cTh + ((size_t)b * SLN + s) * IDF + c0 + c4) = h;
    *(v4bf*)(cTl + ((size_t)b * SLN + s) * IDF + c0 + c4) = l;
  }
}

// -----------------------------------------------------------------------------
// K1 proj: unchanged (known-good).
// -----------------------------------------------------------------------------
__global__ __launch_bounds__(256) void proj_k(const __bf16* __restrict__ cTh,
                                              const __bf16* __restrict__ cTl,
                                              const __bf16* __restrict__ Wh,
                                              const __bf16* __restrict__ Wl,
                                              __bf16* __restrict__ STh,
                                              __bf16* __restrict__ STl,
                                              __bf16* __restrict__ Shv) {
  const int b = blockIdx.y, o0 = blockIdx.x * 32;
  const int t = threadIdx.x, w = t >> 6, lane = t & 63;
  const int lr = lane & 15, lg = lane >> 4;
  const int ws = w >> 1, wq = w & 1;
  __shared__ __bf16 AhL[128][32];
  __shared__ __bf16 AlL[128][32];

  v4f acc[4];
#pragma unroll
  for (int fr = 0; fr < 4; ++fr) acc[fr] = (v4f){0.f, 0.f, 0.f, 0.f};

  const int ra = t >> 1, ca0 = (t & 1) * 2;
  const int swA = (ra >> 1) & 3;
  const int pa0 = (ca0 ^ swA) * 8, pa1 = ((ca0 + 1) ^ swA) * 8;
  const __bf16* pAh = cTh + ((size_t)b * SLN + ra) * IDF + ca0 * 8;
  const __bf16* pAl = cTl + ((size_t)b * SLN + ra) * IDF + ca0 * 8;
  const size_t wOff = (size_t)(o0 + wq * 16 + lr) * IDF + lg * 8;

  uint4 aAh0, aAh1, aAl0, aAl1;
  uint4 bAh0, bAh1, bAl0, bAl1;
  v8bf bhc, blc, bhn, bln;
  aAh0 = *(const uint4*)(pAh);
  aAh1 = *(const uint4*)(pAh + 8);
  aAl0 = *(const uint4*)(pAl);
  aAl1 = *(const uint4*)(pAl + 8);
  bAh0 = *(const uint4*)(pAh + 32);
  bAh1 = *(const uint4*)(pAh + 40);
  bAl0 = *(const uint4*)(pAl + 32);
  bAl1 = *(const uint4*)(pAl + 40);
  bhc = *(const v8bf*)(Wh + wOff);
  blc = *(const v8bf*)(Wl + wOff);

#define PROJ_BODY(S0, S1, S2, S3, IT)                                          \
  {                                                                            \
    lbar();                                                                    \
    *(uint4*)&AhL[ra][pa0] = S0;                                               \
    *(uint4*)&AhL[ra][pa1] = S1;                                               \
    *(uint4*)&AlL[ra][pa0] = S2;                                               \
    *(uint4*)&AlL[ra][pa1] = S3;                                               \
    if ((IT) + 2 < NT) {                                                       \
      S0 = *(const uint4*)(pAh + ((IT) + 2) * 32);                             \
      S1 = *(const uint4*)(pAh + ((IT) + 2) * 32 + 8);                         \
      S2 = *(const uint4*)(pAl + ((IT) + 2) * 32);                             \
      S3 = *(const uint4*)(pAl + ((IT) + 2) * 32 + 8);                         \
    }                                                                          \
    if ((IT) + 1 < NT) {                                                       \
      bhn = *(const v8bf*)(Wh + wOff + ((IT) + 1) * 32);                       \
      bln = *(const v8bf*)(Wl + wOff + ((IT) + 1) * 32);                       \
    }                                                                          \
    lbar();                                                                    \
    _Pragma("unroll") for (int fr = 0; fr < 4; ++fr) {                         \
      const int r = ws * 64 + fr * 16 + lr;                                    \
      const int pp = (lg ^ ((r >> 1) & 3)) * 8;                                \
      v8bf ah = *(const v8bf*)&AhL[r][pp];                                     \
      v8bf al = *(const v8bf*)&AlL[r][pp];                                     \
      acc[fr] = MFMA16(ah, bhc, acc[fr], 0, 0, 0);                             \
      acc[fr] = MFMA16(ah, blc, acc[fr], 0, 0, 0);                             \
      acc[fr] = MFMA16(al, bhc, acc[fr], 0, 0, 0);                             \
    }                                                                          \
    bhc = bhn;                                                                 \
    blc = bln;                                                                 \
  }

  for (int it2 = 0; it2 < NT / 2; ++it2) {
    const int itE = it2 * 2;
    PROJ_BODY(aAh0, aAh1, aAl0, aAl1, itE);
    PROJ_BODY(bAh0, bAh1, bAl0, bAl1, itE + 1);
  }
#undef PROJ_BODY

  const int o = o0 + wq * 16 + lr;
#pragma unroll
  for (int fr = 0; fr < 4; ++fr) {
    __bf16 hp[4];
#pragma unroll
    for (int r = 0; r < 4; ++r) {
      int s = ws * 64 + fr * 16 + lg * 4 + r;
      __bf16 h, l;
      split2(acc[fr][r], h, l);
      STh[((size_t)b * SLN + s) * IDF + o] = h;
      STl[((size_t)b * SLN + s) * IDF + o] = l;
      hp[r] = h;
    }
    *(v4bf*)(Shv + ((size_t)b * IDF + o) * SLN + ws * 64 + fr * 16 + lg * 4) =
        (v4bf){hp[0], hp[1], hp[2], hp[3]};
  }
}

// -----------------------------------------------------------------------------
// K2 qkpv: 1024 threads = 16 waves -> 2 blocks/CU x 16 = 32 waves/CU (HW max).
// Wave w: wq = w&3 (q-16 col), sh = w>>2 (s-quarter of 32 -> 2 frags).
// Staging by thread halves: t<512 stages A-hi + ti (2 gloads/window),
// t>=512 stages A-lo (1 gload/window); counted vmcnt(2)/vmcnt(1) per half
// (wave-uniform branch). Double-buffered, round-14 window structure.
// Softmax: wave-reduce over lg, cross-wave combine of 4 s-quarters via LDS.
// PV: wave = (qf = w&3, i-slab (w>>2)*192); P-frags hoisted, Shv from L2.
// -----------------------------------------------------------------------------
__global__ __launch_bounds__(1024, 8) void qkpv_k(const float* __restrict__ input,
                                                  const __bf16* __restrict__ STh,
                                                  const __bf16* __restrict__ STl,
                                                  const __bf16* __restrict__ Shv,
                                                  const int* __restrict__ mask,
                                                  float* __restrict__ wc,
                                                  float* __restrict__ attn_out) {
  const int bid = blockIdx.x;
  const int nid = (bid & 7) * 64 + (bid >> 3);  // XCD swizzle, 512 blocks
  const int b = nid >> 4, q0 = (nid & 15) * 64;
  const int t = threadIdx.x, w = t >> 6, lane = t & 63;
  const int lr = lane & 15, lg = lane >> 4;
  const int wq = w & 3, sh = w >> 2;

  // LDS: buf0 @0 (Ah 8K | Al 8K | ti 8K) | buf1 @24576 | msk @49152 |
  //      redm @49664 (1K) | reds @50688 (1K). Total 51712 B; 2 blocks/CU.
  __shared__ __align__(16) char lds[51712];
  float* const msk  = (float*)(lds + 49152);
  float* const redm = (float*)(lds + 49664);
  float* const reds = (float*)(lds + 50688);
  char* const PLb = lds;  // P tile (16 KB) overlays buf0 after QK

  if (t < SLN) msk[t] = -10000.0f * (float)mask[b * SLN + t];

  v4f acc[2];
  acc[0] = (v4f){0.f, 0.f, 0.f, 0.f};
  acc[1] = (v4f){0.f, 0.f, 0.f, 0.f};

  // ---- staging maps (verified against round-14 read formulas) ----
  // A (hi for t<512, lo for t>=512): u = t&511; row = u>>2 (128 rows of 64B);
  // stored chunk (u&3) sourced from global chunk (u&3)^((row>>1)&3).
  const int u = t & 511;
  const int raA = u >> 2;
  const int cA  = (u & 3) ^ ((raA >> 1) & 3);
  const __bf16* gA =
      (((t < 512) ? STh : STl) + ((size_t)b * SLN + raA) * IDF) + cA * 8;
  const int dAoff = (t < 512) ? (w * 1024) : (8192 + (w - 8) * 1024);
  // ti (t<512 only): row rT = t>>4 (32 rows of 256B); stored col group (t&15)
  // holds global cols rotated by -16*((w>>1)&1)  [wave-uniform key].
  const int rT = t >> 4;
  const int cT = (((t & 15) * 4) - (((w >> 1) & 1) << 4)) & 63;
  const float* gTi = input + ((size_t)b * IDF + rT) * QLN + q0 + cT;
  const int dToff = 16384 + w * 1024;
  // read-side rotated column for ti
  const int colTi = (wq * 16 + lr + ((lg & 1) << 4)) & 63;

  // prologue: tiles 0,1 (per-wave FIFO: tile0's loads first)
  if (t < 512) {
    gload16(gA, lds + dAoff);
    gload16(gTi, lds + dToff);
    gload16(gA + 32, lds + 24576 + dAoff);
    gload16(gTi + (size_t)32 * QLN, lds + 24576 + dToff);
  } else {
    gload16(gA, lds + dAoff);
    gload16(gA + 32, lds + 24576 + dAoff);
  }

  // window IT: wait own-wave tile IT drained (leave next tile in flight);
  // barrier; compute; lgkm; barrier; issue tile IT+2 into freed buffer.
#define QK_ITER(CUROFF, IT, VA, VB)                                            \
  {                                                                            \
    if (w < 8) {                                                               \
      asm volatile("s_waitcnt vmcnt(" #VA ")" ::: "memory");                   \
    } else {                                                                   \
      asm volatile("s_waitcnt vmcnt(" #VB ")" ::: "memory");                   \
    }                                                                          \
    __builtin_amdgcn_s_barrier();                                              \
    const float* Tb = (const float*)(lds + (CUROFF) + 16384);                  \
    v8bf bh, bl;                                                               \
    _Pragma("unroll") for (int e = 0; e < 8; ++e) {                            \
      __bf16 h, l;                                                             \
      split2(Tb[(lg * 8 + e) * 64 + colTi], h, l);                             \
      bh[e] = h;                                                               \
      bl[e] = l;                                                               \
    }                                                                          \
    const __bf16* Ab = (const __bf16*)(lds + (CUROFF));                        \
    __builtin_amdgcn_s_setprio(1);                                             \
    _Pragma("unroll") for (int fr = 0; fr < 2; ++fr) {                         \
      const int r = sh * 32 + fr * 16 + lr;                                    \
      const int pp = (lg ^ ((r >> 1) & 3)) * 8;                                \
      v8bf ah = *(const v8bf*)(Ab + r * 32 + pp);                              \
      v8bf al = *(const v8bf*)(Ab + 4096 + r * 32 + pp);                       \
      acc[fr] = MFMA16(ah, bh, acc[fr], 0, 0, 0);                              \
      acc[fr] = MFMA16(ah, bl, acc[fr], 0, 0, 0);                              \
      acc[fr] = MFMA16(al, bh, acc[fr], 0, 0, 0);                              \
    }                                                                          \
    __builtin_amdgcn_s_setprio(0);                                             \
    asm volatile("s_waitcnt lgkmcnt(0)" ::: "memory");                         \
    __builtin_amdgcn_s_barrier();                                              \
    if ((IT) + 2 < NT) {                                                       \
      if (t < 512) {                                                           \
        gload16(gA + (size_t)((IT) + 2) * 32, lds + (CUROFF) + dAoff);         \
        gload16(gTi + (size_t)((IT) + 2) * 32 * QLN, lds + (CUROFF) + dToff);  \
      } else {                                                                 \
        gload16(gA + (size_t)((IT) + 2) * 32, lds + (CUROFF) + dAoff);         \
      }                                                                        \
    }                                                                          \
  }

  for (int it2 = 0; it2 < 11; ++it2) {
    const int itE = it2 * 2;
    QK_ITER(0, itE, 2, 1);
    QK_ITER(24576, itE + 1, 2, 1);
  }
  QK_ITER(0, 22, 2, 1);
  QK_ITER(24576, 23, 0, 0);
#undef QK_ITER

  // softmax over s=128 for q = q0 + wq*16 + lr; wave owns s-quarter sh (32 s)
  const int q = q0 + wq * 16 + lr;
  float mx = -3.0e38f;
#pragma unroll
  for (int fr = 0; fr < 2; ++fr)
#pragma unroll
    for (int r = 0; r < 4; ++r) {
      acc[fr][r] += msk[sh * 32 + fr * 16 + lg * 4 + r];
      mx = fmaxf(mx, acc[fr][r]);
    }
  mx = fmaxf(mx, __shfl_xor(mx, 16));
  mx = fmaxf(mx, __shfl_xor(mx, 32));
  if (lg == 0) redm[sh * 64 + wq * 16 + lr] = mx;
  __syncthreads();
  {
    const int o = wq * 16 + lr;
    mx = fmaxf(fmaxf(redm[o], redm[64 + o]),
               fmaxf(redm[128 + o], redm[192 + o]));
  }
  float sum = 0.f;
#pragma unroll
  for (int fr = 0; fr < 2; ++fr)
#pragma unroll
    for (int r = 0; r < 4; ++r) {
      float e = __expf(acc[fr][r] - mx);
      acc[fr][r] = e;
      sum += e;
    }
  sum += __shfl_xor(sum, 16);
  sum += __shfl_xor(sum, 32);
  if (lg == 0) reds[sh * 64 + wq * 16 + lr] = sum;
  __syncthreads();
  float inv;
  {
    const int o = wq * 16 + lr;
    inv = 1.0f / (reds[o] + reds[64 + o] + reds[128 + o] + reds[192 + o]);
  }
  const int qloc = wq * 16 + lr;
#pragma unroll
  for (int fr = 0; fr < 2; ++fr) {
    __bf16 hp[4];
#pragma unroll
    for (int r = 0; r < 4; ++r) {
      float p = acc[fr][r] * inv;
      attn_out[((size_t)b * SLN + sh * 32 + fr * 16 + lg * 4 + r) * QLN + q] = p;
      hp[r] = (__bf16)p;
    }
    // PL swizzled write (overlays buf0): s0 = sh*32 + fr*16 + lg*4
    const int g = (sh * 4 + fr * 2 + (lg >> 1)) ^ lr;
    *(v4bf*)(PLb + qloc * 256 + g * 16 + (lg & 1) * 8) =
        (v4bf){hp[0], hp[1], hp[2], hp[3]};
  }
  __syncthreads();

  // ---- PV phase: wave -> (q-frag qf = w&3, i-slab (w>>2)*192) ----
  const int qf = w & 3;
  const int islab = (w >> 2) * 192;
  v8bf pav[4];
#pragma unroll
  for (int kt = 0; kt < 4; ++kt) {
    const int g0 = (kt * 4 + lg) ^ lr;
    pav[kt] = *(const v8bf*)(PLb + (qf * 16 + lr) * 256 + g0 * 16);
  }
  const __bf16* pShv = Shv + ((size_t)b * IDF + islab + lr) * SLN + lg * 8;
  float* pWc = wc + ((size_t)b * IDF + islab + lr) * QLN + q0 + qf * 16 + lg * 4;
#pragma unroll 3
  for (int ifr = 0; ifr < 12; ++ifr) {
    v4f a0 = (v4f){0.f, 0.f, 0.f, 0.f};
#pragma unroll
    for (int kt = 0; kt < 4; ++kt) {
      v8bf bb = *(const v8bf*)(pShv + (size_t)(ifr * 16) * SLN + kt * 32);
      a0 = MFMA16(pav[kt], bb, a0, 0, 0, 0);
    }
    *(float4*)(pWc + (size_t)(ifr * 16) * QLN) =
        make_float4(a0[0], a0[1], a0[2], a0[3]);
  }
}

// -----------------------------------------------------------------------------
extern "C" void kernel_launch(void* const* d_in, const int* in_sizes, int n_in,
                              void* d_out, int out_size, void* d_ws, size_t ws_size,
                              hipStream_t stream) {
  const float* input   = (const float*)d_in[0];
  const float* context = (const float*)d_in[1];
  const int*   mask    = (const int*)d_in[2];
  const float* w_conv  = (const float*)d_in[3];

  float* out      = (float*)d_out;
  float* wc       = out;
  float* attn_out = out + (size_t)NB * IDF * QLN;

  const size_t SE = (size_t)NB * SLN * IDF;  // 3,145,728
  const size_t WE = (size_t)IDF * IDF;       // 589,824
  __bf16* wsb = (__bf16*)d_ws;
  __bf16* STh = wsb;
  __bf16* STl = STh + SE;
  __bf16* Shv = STl + SE;
  __bf16* scr = (__bf16*)wc;  // scratch in output region (dead before PV)
  __bf16* cTh = scr;
  __bf16* cTl = cTh + SE;
  __bf16* Wh  = cTl + SE;
  __bf16* Wl  = Wh + WE;

  prep_k<<<960, 256, 0, stream>>>(w_conv, context, Wh, Wl, cTh, cTl);
  proj_k<<<dim3(24, NB), 256, 0, stream>>>(cTh, cTl, Wh, Wl, STh, STl, Shv);
  qkpv_k<<<512, 1024, 0, stream>>>(input, STh, STl, Shv, mask, wc, attn_out);
}

// Round 18
// 116.423 us; speedup vs baseline: 1.6650x; 1.0721x over previous
//
#include <hip/hip_runtime.h>

#define NB  32
#define IDF 768
#define SLN 128
#define QLN 1024
#define NT  24   // IDF/32 k-tiles (even)

typedef __bf16 v8bf __attribute__((ext_vector_type(8)));
typedef __bf16 v4bf __attribute__((ext_vector_type(4)));
typedef float  v4f  __attribute__((ext_vector_type(4)));

#define MFMA16 __builtin_amdgcn_mfma_f32_16x16x32_bf16

__device__ __forceinline__ void split2(float x, __bf16& h, __bf16& l) {
  h = (__bf16)x;
  l = (__bf16)(x - (float)h);
}

__device__ __forceinline__ void gload16(const void* g, void* l) {
  __builtin_amdgcn_global_load_lds(
      (const __attribute__((address_space(1))) void*)g,
      (__attribute__((address_space(3))) void*)l, 16, 0, 0);
}

__device__ __forceinline__ void lbar() {
  asm volatile("s_waitcnt lgkmcnt(0)" ::: "memory");
  __builtin_amdgcn_sched_barrier(0);
  __builtin_amdgcn_s_barrier();
  __builtin_amdgcn_sched_barrier(0);
}

// -----------------------------------------------------------------------------
// K0 prep: blocks 0..575 split W -> Wh/Wl; blocks 576..959 transpose+split ctx.
// -----------------------------------------------------------------------------
__global__ __launch_bounds__(256) void prep_k(const float* __restrict__ W,
                                              const float* __restrict__ ctx,
                                              __bf16* __restrict__ Wh,
                                              __bf16* __restrict__ Wl,
                                              __bf16* __restrict__ cTh,
                                              __bf16* __restrict__ cTl) {
  const int bid = blockIdx.x, t = threadIdx.x;
  __shared__ float tl[64][133];
  if (bid < 576) {
    int idx = bid * 1024 + t * 4;
    float4 v = *(const float4*)(W + idx);
    float vals[4] = {v.x, v.y, v.z, v.w};
    v4bf h, l;
#pragma unroll
    for (int e = 0; e < 4; ++e) {
      __bf16 hh, ll;
      split2(vals[e], hh, ll);
      h[e] = hh;
      l[e] = ll;
    }
    *(v4bf*)(Wh + idx) = h;
    *(v4bf*)(Wl + idx) = l;
    return;
  }
  const int cid = bid - 576;
  const int b = cid / 12, c0 = (cid % 12) * 64;
#pragma unroll
  for (int j = 0; j < 8; ++j) {
    int u = j * 256 + t;
    int c = u >> 5, s4 = (u & 31) * 4;
    *(float4*)&tl[c][s4] =
        *(const float4*)(ctx + ((size_t)b * IDF + c0 + c) * SLN + s4);
  }
  __syncthreads();
#pragma unroll
  for (int j = 0; j < 8; ++j) {
    int u = j * 256 + t;
    int s = u >> 4, c4 = (u & 15) * 4;
    v4bf h, l;
#pragma unroll
    for (int e = 0; e < 4; ++e) {
      __bf16 hh, ll;
      split2(tl[c4 + e][s], hh, ll);
      h[e] = hh;
      l[e] = ll;
    }
    *(v4bf*)(cTh + ((size_t)b * SLN + s) * IDF + c0 + c4) = h;
    *(v4bf*)(cTl + ((size_t)b * SLN + s) * IDF + c0 + c4) = l;
  }
}

// -----------------------------------------------------------------------------
// K1 proj: unchanged (known-good).
// -----------------------------------------------------------------------------
__global__ __launch_bounds__(256) void proj_k(const __bf16* __restrict__ cTh,
                                              const __bf16* __restrict__ cTl,
                                              const __bf16* __restrict__ Wh,
                                              const __bf16* __restrict__ Wl,
                                              __bf16* __restrict__ STh,
                                              __bf16* __restrict__ STl,
                                              __bf16* __restrict__ Shv) {
  const int b = blockIdx.y, o0 = blockIdx.x * 32;
  const int t = threadIdx.x, w = t >> 6, lane = t & 63;
  const int lr = lane & 15, lg = lane >> 4;
  const int ws = w >> 1, wq = w & 1;
  __shared__ __bf16 AhL[128][32];
  __shared__ __bf16 AlL[128][32];

  v4f acc[4];
#pragma unroll
  for (int fr = 0; fr < 4; ++fr) acc[fr] = (v4f){0.f, 0.f, 0.f, 0.f};

  const int ra = t >> 1, ca0 = (t & 1) * 2;
  const int swA = (ra >> 1) & 3;
  const int pa0 = (ca0 ^ swA) * 8, pa1 = ((ca0 + 1) ^ swA) * 8;
  const __bf16* pAh = cTh + ((size_t)b * SLN + ra) * IDF + ca0 * 8;
  const __bf16* pAl = cTl + ((size_t)b * SLN + ra) * IDF + ca0 * 8;
  const size_t wOff = (size_t)(o0 + wq * 16 + lr) * IDF + lg * 8;

  uint4 aAh0, aAh1, aAl0, aAl1;
  uint4 bAh0, bAh1, bAl0, bAl1;
  v8bf bhc, blc, bhn, bln;
  aAh0 = *(const uint4*)(pAh);
  aAh1 = *(const uint4*)(pAh + 8);
  aAl0 = *(const uint4*)(pAl);
  aAl1 = *(const uint4*)(pAl + 8);
  bAh0 = *(const uint4*)(pAh + 32);
  bAh1 = *(const uint4*)(pAh + 40);
  bAl0 = *(const uint4*)(pAl + 32);
  bAl1 = *(const uint4*)(pAl + 40);
  bhc = *(const v8bf*)(Wh + wOff);
  blc = *(const v8bf*)(Wl + wOff);

#define PROJ_BODY(S0, S1, S2, S3, IT)                                          \
  {                                                                            \
    lbar();                                                                    \
    *(uint4*)&AhL[ra][pa0] = S0;                                               \
    *(uint4*)&AhL[ra][pa1] = S1;                                               \
    *(uint4*)&AlL[ra][pa0] = S2;                                               \
    *(uint4*)&AlL[ra][pa1] = S3;                                               \
    if ((IT) + 2 < NT) {                                                       \
      S0 = *(const uint4*)(pAh + ((IT) + 2) * 32);                             \
      S1 = *(const uint4*)(pAh + ((IT) + 2) * 32 + 8);                         \
      S2 = *(const uint4*)(pAl + ((IT) + 2) * 32);                             \
      S3 = *(const uint4*)(pAl + ((IT) + 2) * 32 + 8);                         \
    }                                                                          \
    if ((IT) + 1 < NT) {                                                       \
      bhn = *(const v8bf*)(Wh + wOff + ((IT) + 1) * 32);                       \
      bln = *(const v8bf*)(Wl + wOff + ((IT) + 1) * 32);                       \
    }                                                                          \
    lbar();                                                                    \
    _Pragma("unroll") for (int fr = 0; fr < 4; ++fr) {                         \
      const int r = ws * 64 + fr * 16 + lr;                                    \
      const int pp = (lg ^ ((r >> 1) & 3)) * 8;                                \
      v8bf ah = *(const v8bf*)&AhL[r][pp];                                     \
      v8bf al = *(const v8bf*)&AlL[r][pp];                                     \
      acc[fr] = MFMA16(ah, bhc, acc[fr], 0, 0, 0);                             \
      acc[fr] = MFMA16(ah, blc, acc[fr], 0, 0, 0);                             \
      acc[fr] = MFMA16(al, bhc, acc[fr], 0, 0, 0);                             \
    }                                                                          \
    bhc = bhn;                                                                 \
    blc = bln;                                                                 \
  }

  for (int it2 = 0; it2 < NT / 2; ++it2) {
    const int itE = it2 * 2;
    PROJ_BODY(aAh0, aAh1, aAl0, aAl1, itE);
    PROJ_BODY(bAh0, bAh1, bAl0, bAl1, itE + 1);
  }
#undef PROJ_BODY

  const int o = o0 + wq * 16 + lr;
#pragma unroll
  for (int fr = 0; fr < 4; ++fr) {
    __bf16 hp[4];
#pragma unroll
    for (int r = 0; r < 4; ++r) {
      int s = ws * 64 + fr * 16 + lg * 4 + r;
      __bf16 h, l;
      split2(acc[fr][r], h, l);
      STh[((size_t)b * SLN + s) * IDF + o] = h;
      STl[((size_t)b * SLN + s) * IDF + o] = l;
      hp[r] = h;
    }
    *(v4bf*)(Shv + ((size_t)b * IDF + o) * SLN + ws * 64 + fr * 16 + lg * 4) =
        (v4bf){hp[0], hp[1], hp[2], hp[3]};
  }
}

// -----------------------------------------------------------------------------
// K2 qkpv: LDS-op-minimized QK. Wave w: wqp = w&1 (2 q-frags), sh = w>>1
// (s-quarter, 2 fr). A via gload_lds (XOR-presourced, linear LDS), only
// 4 ds_read_b128/wave/window (2x less redundancy). B (input) read DIRECTLY
// from global per-lane (64B-coalesced over lr), prefetched 1 window ahead
// into named even/odd reg sets, split in-reg. NO ti in LDS.
// vmcnt: entry 18 steady (B(t)16+A(t+1)2 younger than A(t)); final 16.
// Per-acc MFMA chain order preserved -> bit-identical outputs.
// -----------------------------------------------------------------------------
__global__ __launch_bounds__(512, 4) void qkpv_k(const float* __restrict__ input,
                                                 const __bf16* __restrict__ STh,
                                                 const __bf16* __restrict__ STl,
                                                 const __bf16* __restrict__ Shv,
                                                 const int* __restrict__ mask,
                                                 float* __restrict__ wc,
                                                 float* __restrict__ attn_out) {
  const int bid = blockIdx.x;
  const int nid = (bid & 7) * 64 + (bid >> 3);  // XCD swizzle, 512 blocks
  const int b = nid >> 4, q0 = (nid & 15) * 64;
  const int t = threadIdx.x, w = t >> 6, lane = t & 63;
  const int lr = lane & 15, lg = lane >> 4;
  const int wqp = w & 1, sh = w >> 1;

  // LDS: buf0 @0 (Ah 8K | Al 8K), buf1 @16384, msk @32768, redm @33280 (1K),
  // reds @34304 (1K). Total 35328 B. PL (16 KB) overlays buf0 after QK.
  __shared__ __align__(16) char lds[35328];
  float* const msk  = (float*)(lds + 32768);
  float* const redm = (float*)(lds + 33280);
  float* const reds = (float*)(lds + 34304);
  char* const PLb = lds;

  if (t < SLN) msk[t] = -10000.0f * (float)mask[b * SLN + t];

  v4f acc[2][2];
#pragma unroll
  for (int fr = 0; fr < 2; ++fr)
#pragma unroll
    for (int j = 0; j < 2; ++j) acc[fr][j] = (v4f){0.f, 0.f, 0.f, 0.f};

  // A staging (gload, round-14-verified map): wave w rows w*16..+16
  const int raA = w * 16 + (lane >> 2);
  const int cA  = (lane & 3) ^ ((raA >> 1) & 3);  // inverse of read-side XOR
  const __bf16* gAh = STh + ((size_t)b * SLN + raA) * IDF + cA * 8;
  const __bf16* gAl = STl + ((size_t)b * SLN + raA) * IDF + cA * 8;
  const int dAh = w * 1024, dAl = 8192 + w * 1024;  // bytes within buffer

  // B direct-global: lane (lg,lr), q cols for j=0,1
  const float* gB = input + (size_t)b * IDF * QLN + q0 + wqp * 32 + lr;
  // element (window IT, j, e): gB[(IT*32 + lg*8 + e)*QLN + j*16]

  // prologue: A(0), A(1) gloads; B(0) regs
  gload16(gAh, lds + dAh);
  gload16(gAl, lds + dAl);
  gload16(gAh + 32, lds + 16384 + dAh);
  gload16(gAl + 32, lds + 16384 + dAl);
  float aB[2][8], bB[2][8];
#pragma unroll
  for (int j = 0; j < 2; ++j)
#pragma unroll
    for (int e = 0; e < 8; ++e)
      aB[j][e] = gB[(size_t)(lg * 8 + e) * QLN + j * 16];

#define QK_WIN(CUROFF, BCUR, BNXT, IT, VMC)                                    \
  {                                                                            \
    asm volatile("s_waitcnt vmcnt(" #VMC ")" ::: "memory");                    \
    __builtin_amdgcn_sched_barrier(0);                                         \
    __builtin_amdgcn_s_barrier();                                              \
    __builtin_amdgcn_sched_barrier(0);                                         \
    if ((IT) + 1 < NT) {                                                       \
      _Pragma("unroll") for (int j = 0; j < 2; ++j)                            \
          _Pragma("unroll") for (int e = 0; e < 8; ++e)                        \
          BNXT[j][e] =                                                         \
              gB[(size_t)(((IT) + 1) * 32 + lg * 8 + e) * QLN + j * 16];       \
    }                                                                          \
    __builtin_amdgcn_sched_barrier(0);                                         \
    v8bf bh[2], bl[2];                                                         \
    _Pragma("unroll") for (int j = 0; j < 2; ++j)                              \
        _Pragma("unroll") for (int e = 0; e < 8; ++e) {                        \
      __bf16 h, l;                                                             \
      split2(BCUR[j][e], h, l);                                                \
      bh[j][e] = h;                                                            \
      bl[j][e] = l;                                                            \
    }                                                                          \
    const __bf16* Ab = (const __bf16*)(lds + (CUROFF));                        \
    __builtin_amdgcn_s_setprio(1);                                             \
    _Pragma("unroll") for (int fr = 0; fr < 2; ++fr) {                         \
      const int r = sh * 32 + fr * 16 + lr;                                    \
      const int pp = (lg ^ ((r >> 1) & 3)) * 8;                                \
      v8bf ah = *(const v8bf*)(Ab + r * 32 + pp);                              \
      v8bf al = *(const v8bf*)(Ab + 4096 + r * 32 + pp);                       \
      _Pragma("unroll") for (int j = 0; j < 2; ++j) {                          \
        acc[fr][j] = MFMA16(ah, bh[j], acc[fr][j], 0, 0, 0);                   \
        acc[fr][j] = MFMA16(ah, bl[j], acc[fr][j], 0, 0, 0);                   \
        acc[fr][j] = MFMA16(al, bh[j], acc[fr][j], 0, 0, 0);                   \
      }                                                                        \
    }                                                                          \
    __builtin_amdgcn_s_setprio(0);                                             \
    asm volatile("s_waitcnt lgkmcnt(0)" ::: "memory");                         \
    __builtin_amdgcn_s_barrier();                                              \
    if ((IT) + 2 < NT) {                                                       \
      gload16(gAh + (size_t)((IT) + 2) * 32, lds + (CUROFF) + dAh);            \
      gload16(gAl + (size_t)((IT) + 2) * 32, lds + (CUROFF) + dAl);            \
    }                                                                          \
  }

  for (int it2 = 0; it2 < 11; ++it2) {
    const int itE = it2 * 2;
    QK_WIN(0, aB, bB, itE, 18);
    QK_WIN(16384, bB, aB, itE + 1, 18);
  }
  QK_WIN(0, aB, bB, 22, 18);
  QK_WIN(16384, bB, aB, 23, 16);
#undef QK_WIN

  // softmax over s=128; lane covers q = q0 + (wqp*2+j)*16 + lr, s-quarter sh
  float mx[2], sum[2];
#pragma unroll
  for (int j = 0; j < 2; ++j) {
    mx[j] = -3.0e38f;
#pragma unroll
    for (int fr = 0; fr < 2; ++fr)
#pragma unroll
      for (int r = 0; r < 4; ++r) {
        acc[fr][j][r] += msk[sh * 32 + fr * 16 + lg * 4 + r];
        mx[j] = fmaxf(mx[j], acc[fr][j][r]);
      }
    mx[j] = fmaxf(mx[j], __shfl_xor(mx[j], 16));
    mx[j] = fmaxf(mx[j], __shfl_xor(mx[j], 32));
    if (lg == 0) redm[sh * 64 + wqp * 32 + j * 16 + lr] = mx[j];
  }
  __syncthreads();
#pragma unroll
  for (int j = 0; j < 2; ++j) {
    const int qh = wqp * 32 + j * 16 + lr;
    mx[j] = fmaxf(fmaxf(redm[qh], redm[64 + qh]),
                  fmaxf(redm[128 + qh], redm[192 + qh]));
    sum[j] = 0.f;
#pragma unroll
    for (int fr = 0; fr < 2; ++fr)
#pragma unroll
      for (int r = 0; r < 4; ++r) {
        float e = __expf(acc[fr][j][r] - mx[j]);
        acc[fr][j][r] = e;
        sum[j] += e;
      }
    sum[j] += __shfl_xor(sum[j], 16);
    sum[j] += __shfl_xor(sum[j], 32);
    if (lg == 0) reds[sh * 64 + wqp * 32 + j * 16 + lr] = sum[j];
  }
  __syncthreads();
#pragma unroll
  for (int j = 0; j < 2; ++j) {
    const int qh = wqp * 32 + j * 16 + lr;
    const float inv =
        1.0f / (reds[qh] + reds[64 + qh] + reds[128 + qh] + reds[192 + qh]);
    const int q = q0 + qh;
#pragma unroll
    for (int fr = 0; fr < 2; ++fr) {
      __bf16 hp[4];
#pragma unroll
      for (int r = 0; r < 4; ++r) {
        float p = acc[fr][j][r] * inv;
        attn_out[((size_t)b * SLN + sh * 32 + fr * 16 + lg * 4 + r) * QLN + q] =
            p;
        hp[r] = (__bf16)p;
      }
      const int g = (sh * 4 + fr * 2 + (lg >> 1)) ^ lr;
      *(v4bf*)(PLb + qh * 256 + g * 16 + (lg & 1) * 8) =
          (v4bf){hp[0], hp[1], hp[2], hp[3]};
    }
  }
  __syncthreads();

  // ---- PV phase (round-14 verified): wave -> (qfp=(w&1)*2, islab (w>>1)*192)
  const int qfp = (w & 1) * 2;
  const int islab = (w >> 1) * 192;
  v8bf pa0v[4], pa1v[4];
#pragma unroll
  for (int kt = 0; kt < 4; ++kt) {
    const int g0 = (kt * 4 + lg) ^ lr;
    pa0v[kt] = *(const v8bf*)(PLb + (qfp * 16 + lr) * 256 + g0 * 16);
    pa1v[kt] = *(const v8bf*)(PLb + ((qfp + 1) * 16 + lr) * 256 + g0 * 16);
  }
  const __bf16* pShv = Shv + ((size_t)b * IDF + islab + lr) * SLN + lg * 8;
  float* pWc = wc + ((size_t)b * IDF + islab + lr) * QLN + q0;
#pragma unroll 2
  for (int ifr = 0; ifr < 12; ++ifr) {
    v4f a0 = (v4f){0.f, 0.f, 0.f, 0.f};
    v4f a1 = (v4f){0.f, 0.f, 0.f, 0.f};
#pragma unroll
    for (int kt = 0; kt < 4; ++kt) {
      v8bf bb = *(const v8bf*)(pShv + (size_t)(ifr * 16) * SLN + kt * 32);
      a0 = MFMA16(pa0v[kt], bb, a0, 0, 0, 0);
      a1 = MFMA16(pa1v[kt], bb, a1, 0, 0, 0);
    }
    *(float4*)(pWc + (size_t)(ifr * 16) * QLN + qfp * 16 + lg * 4) =
        make_float4(a0[0], a0[1], a0[2], a0[3]);
    *(float4*)(pWc + (size_t)(ifr * 16) * QLN + (qfp + 1) * 16 + lg * 4) =
        make_float4(a1[0], a1[1], a1[2], a1[3]);
  }
}

// -----------------------------------------------------------------------------
extern "C" void kernel_launch(void* const* d_in, const int* in_sizes, int n_in,
                              void* d_out, int out_size, void* d_ws, size_t ws_size,
                              hipStream_t stream) {
  const float* input   = (const float*)d_in[0];
  const float* context = (const float*)d_in[1];
  const int*   mask    = (const int*)d_in[2];
  const float* w_conv  = (const float*)d_in[3];

  float* out      = (float*)d_out;
  float* wc       = out;
  float* attn_out = out + (size_t)NB * IDF * QLN;

  const size_t SE = (size_t)NB * SLN * IDF;  // 3,145,728
  const size_t WE = (size_t)IDF * IDF;       // 589,824
  __bf16* wsb = (__bf16*)d_ws;
  __bf16* STh = wsb;
  __bf16* STl = STh + SE;
  __bf16* Shv = STl + SE;
  __bf16* scr = (__bf16*)wc;  // scratch in output region (dead before PV)
  __bf16* cTh = scr;
  __bf16* cTl = cTh + SE;
  __bf16* Wh  = cTl + SE;
  __bf16* Wl  = Wh + WE;

  prep_k<<<960, 256, 0, stream>>>(w_conv, context, Wh, Wl, cTh, cTl);
  proj_k<<<dim3(24, NB), 256, 0, stream>>>(cTh, cTl, Wh, Wl, STh, STl, Shv);
  qkpv_k<<<512, 512, 0, stream>>>(input, STh, STl, Shv, mask, wc, attn_out);
}

// Round 19
// 108.963 us; speedup vs baseline: 1.7789x; 1.0685x over previous
//
#include <hip/hip_runtime.h>

#define NB  32
#define IDF 768
#define SLN 128
#define QLN 1024
#define NT  24   // IDF/32 k-tiles (even)

typedef __bf16 v8bf __attribute__((ext_vector_type(8)));
typedef __bf16 v4bf __attribute__((ext_vector_type(4)));
typedef float  v4f  __attribute__((ext_vector_type(4)));

#define MFMA16 __builtin_amdgcn_mfma_f32_16x16x32_bf16

__device__ __forceinline__ void split2(float x, __bf16& h, __bf16& l) {
  h = (__bf16)x;
  l = (__bf16)(x - (float)h);
}

__device__ __forceinline__ void gload16(const void* g, void* l) {
  __builtin_amdgcn_global_load_lds(
      (const __attribute__((address_space(1))) void*)g,
      (__attribute__((address_space(3))) void*)l, 16, 0, 0);
}

__device__ __forceinline__ void lbar() {
  asm volatile("s_waitcnt lgkmcnt(0)" ::: "memory");
  __builtin_amdgcn_sched_barrier(0);
  __builtin_amdgcn_s_barrier();
  __builtin_amdgcn_sched_barrier(0);
}

// -----------------------------------------------------------------------------
// K0 prep: blocks 0..575 split W -> Wh/Wl; blocks 576..959 transpose+split ctx.
// -----------------------------------------------------------------------------
__global__ __launch_bounds__(256) void prep_k(const float* __restrict__ W,
                                              const float* __restrict__ ctx,
                                              __bf16* __restrict__ Wh,
                                              __bf16* __restrict__ Wl,
                                              __bf16* __restrict__ cTh,
                                              __bf16* __restrict__ cTl) {
  const int bid = blockIdx.x, t = threadIdx.x;
  __shared__ float tl[64][133];
  if (bid < 576) {
    int idx = bid * 1024 + t * 4;
    float4 v = *(const float4*)(W + idx);
    float vals[4] = {v.x, v.y, v.z, v.w};
    v4bf h, l;
#pragma unroll
    for (int e = 0; e < 4; ++e) {
      __bf16 hh, ll;
      split2(vals[e], hh, ll);
      h[e] = hh;
      l[e] = ll;
    }
    *(v4bf*)(Wh + idx) = h;
    *(v4bf*)(Wl + idx) = l;
    return;
  }
  const int cid = bid - 576;
  const int b = cid / 12, c0 = (cid % 12) * 64;
#pragma unroll
  for (int j = 0; j < 8; ++j) {
    int u = j * 256 + t;
    int c = u >> 5, s4 = (u & 31) * 4;
    *(float4*)&tl[c][s4] =
        *(const float4*)(ctx + ((size_t)b * IDF + c0 + c) * SLN + s4);
  }
  __syncthreads();
#pragma unroll
  for (int j = 0; j < 8; ++j) {
    int u = j * 256 + t;
    int s = u >> 4, c4 = (u & 15) * 4;
    v4bf h, l;
#pragma unroll
    for (int e = 0; e < 4; ++e) {
      __bf16 hh, ll;
      split2(tl[c4 + e][s], hh, ll);
      h[e] = hh;
      l[e] = ll;
    }
    *(v4bf*)(cTh + ((size_t)b * SLN + s) * IDF + c0 + c4) = h;
    *(v4bf*)(cTl + ((size_t)b * SLN + s) * IDF + c0 + c4) = l;
  }
}

// -----------------------------------------------------------------------------
// K1 proj: unchanged (known-good).
// -----------------------------------------------------------------------------
__global__ __launch_bounds__(256) void proj_k(const __bf16* __restrict__ cTh,
                                              const __bf16* __restrict__ cTl,
                                              const __bf16* __restrict__ Wh,
                                              const __bf16* __restrict__ Wl,
                                              __bf16* __restrict__ STh,
                                              __bf16* __restrict__ STl,
                                              __bf16* __restrict__ Shv) {
  const int b = blockIdx.y, o0 = blockIdx.x * 32;
  const int t = threadIdx.x, w = t >> 6, lane = t & 63;
  const int lr = lane & 15, lg = lane >> 4;
  const int ws = w >> 1, wq = w & 1;
  __shared__ __bf16 AhL[128][32];
  __shared__ __bf16 AlL[128][32];

  v4f acc[4];
#pragma unroll
  for (int fr = 0; fr < 4; ++fr) acc[fr] = (v4f){0.f, 0.f, 0.f, 0.f};

  const int ra = t >> 1, ca0 = (t & 1) * 2;
  const int swA = (ra >> 1) & 3;
  const int pa0 = (ca0 ^ swA) * 8, pa1 = ((ca0 + 1) ^ swA) * 8;
  const __bf16* pAh = cTh + ((size_t)b * SLN + ra) * IDF + ca0 * 8;
  const __bf16* pAl = cTl + ((size_t)b * SLN + ra) * IDF + ca0 * 8;
  const size_t wOff = (size_t)(o0 + wq * 16 + lr) * IDF + lg * 8;

  uint4 aAh0, aAh1, aAl0, aAl1;
  uint4 bAh0, bAh1, bAl0, bAl1;
  v8bf bhc, blc, bhn, bln;
  aAh0 = *(const uint4*)(pAh);
  aAh1 = *(const uint4*)(pAh + 8);
  aAl0 = *(const uint4*)(pAl);
  aAl1 = *(const uint4*)(pAl + 8);
  bAh0 = *(const uint4*)(pAh + 32);
  bAh1 = *(const uint4*)(pAh + 40);
  bAl0 = *(const uint4*)(pAl + 32);
  bAl1 = *(const uint4*)(pAl + 40);
  bhc = *(const v8bf*)(Wh + wOff);
  blc = *(const v8bf*)(Wl + wOff);

#define PROJ_BODY(S0, S1, S2, S3, IT)                                          \
  {                                                                            \
    lbar();                                                                    \
    *(uint4*)&AhL[ra][pa0] = S0;                                               \
    *(uint4*)&AhL[ra][pa1] = S1;                                               \
    *(uint4*)&AlL[ra][pa0] = S2;                                               \
    *(uint4*)&AlL[ra][pa1] = S3;                                               \
    if ((IT) + 2 < NT) {                                                       \
      S0 = *(const uint4*)(pAh + ((IT) + 2) * 32);                             \
      S1 = *(const uint4*)(pAh + ((IT) + 2) * 32 + 8);                         \
      S2 = *(const uint4*)(pAl + ((IT) + 2) * 32);                             \
      S3 = *(const uint4*)(pAl + ((IT) + 2) * 32 + 8);                         \
    }                                                                          \
    if ((IT) + 1 < NT) {                                                       \
      bhn = *(const v8bf*)(Wh + wOff + ((IT) + 1) * 32);                       \
      bln = *(const v8bf*)(Wl + wOff + ((IT) + 1) * 32);                       \
    }                                                                          \
    lbar();                                                                    \
    _Pragma("unroll") for (int fr = 0; fr < 4; ++fr) {                         \
      const int r = ws * 64 + fr * 16 + lr;                                    \
      const int pp = (lg ^ ((r >> 1) & 3)) * 8;                                \
      v8bf ah = *(const v8bf*)&AhL[r][pp];                                     \
      v8bf al = *(const v8bf*)&AlL[r][pp];                                     \
      acc[fr] = MFMA16(ah, bhc, acc[fr], 0, 0, 0);                             \
      acc[fr] = MFMA16(ah, blc, acc[fr], 0, 0, 0);                             \
      acc[fr] = MFMA16(al, bhc, acc[fr], 0, 0, 0);                             \
    }                                                                          \
    bhc = bhn;                                                                 \
    blc = bln;                                                                 \
  }

  for (int it2 = 0; it2 < NT / 2; ++it2) {
    const int itE = it2 * 2;
    PROJ_BODY(aAh0, aAh1, aAl0, aAl1, itE);
    PROJ_BODY(bAh0, bAh1, bAl0, bAl1, itE + 1);
  }
#undef PROJ_BODY

  const int o = o0 + wq * 16 + lr;
#pragma unroll
  for (int fr = 0; fr < 4; ++fr) {
    __bf16 hp[4];
#pragma unroll
    for (int r = 0; r < 4; ++r) {
      int s = ws * 64 + fr * 16 + lg * 4 + r;
      __bf16 h, l;
      split2(acc[fr][r], h, l);
      STh[((size_t)b * SLN + s) * IDF + o] = h;
      STl[((size_t)b * SLN + s) * IDF + o] = l;
      hp[r] = h;
    }
    *(v4bf*)(Shv + ((size_t)b * IDF + o) * SLN + ws * 64 + fr * 16 + lg * 4) =
        (v4bf){hp[0], hp[1], hp[2], hp[3]};
  }
}

// -----------------------------------------------------------------------------
// K2 qkpv: 256-thread blocks -> 4 independent barrier domains/CU (LDS 34.8KB).
// 4 waves: wqp = w&1 (2 q-frags j), sh2 = w>>1 (s-half, 4 fr). acc[4][2];
// 24 MFMA/wave/window. A via gload_lds (4 instrs/wave/window: hi/lo x two
// 16-row groups; XOR key invariant under +16 rows so one pointer serves both).
// B direct-global per-lane regs, prefetched 1 window ahead. FIFO vmcnt:
// steady 4 (keep A(t+1)), final 0. Logit MFMA chain order preserved.
// -----------------------------------------------------------------------------
__global__ __launch_bounds__(256, 4) void qkpv_k(const float* __restrict__ input,
                                                 const __bf16* __restrict__ STh,
                                                 const __bf16* __restrict__ STl,
                                                 const __bf16* __restrict__ Shv,
                                                 const int* __restrict__ mask,
                                                 float* __restrict__ wc,
                                                 float* __restrict__ attn_out) {
  const int bid = blockIdx.x;
  const int nid = (bid & 7) * 64 + (bid >> 3);  // XCD swizzle, 512 blocks
  const int b = nid >> 4, q0 = (nid & 15) * 64;
  const int t = threadIdx.x, w = t >> 6, lane = t & 63;
  const int lr = lane & 15, lg = lane >> 4;
  const int wqp = w & 1, sh2 = w >> 1;

  // LDS: buf0 @0 (Ah 8K | Al 8K), buf1 @16384, msk @32768 (512B),
  // redm @33280 (512B), reds @33792 (512B). Total 34816 B -> 4 blocks/CU.
  __shared__ __align__(16) char lds[34816];
  float* const msk  = (float*)(lds + 32768);
  float* const redm = (float*)(lds + 33280);
  float* const reds = (float*)(lds + 33792);
  char* const PLb = lds;  // P tile (16 KB) overlays buf0 after QK

  if (t < SLN) msk[t] = -10000.0f * (float)mask[b * SLN + t];

  v4f acc[4][2];
#pragma unroll
  for (int fr = 0; fr < 4; ++fr)
#pragma unroll
    for (int j = 0; j < 2; ++j) acc[fr][j] = (v4f){0.f, 0.f, 0.f, 0.f};

  // A staging: wave w stages rows [w*32, w*32+32) for hi AND lo, as two
  // 16-row gloads each. raA0 = base row; XOR key (raA0>>1)&3 is invariant
  // under +16 rows, so gA + q*16*IDF reuses the same cA.
  const int raA0 = w * 32 + (lane >> 2);
  const int cA   = (lane & 3) ^ ((raA0 >> 1) & 3);
  const __bf16* gAh = STh + ((size_t)b * SLN + raA0) * IDF + cA * 8;
  const __bf16* gAl = STl + ((size_t)b * SLN + raA0) * IDF + cA * 8;
  const int dAh = w * 2048;          // bytes (hi region 0..8191)
  const int dAl = 8192 + w * 2048;   // lo region

  // B direct-global: lane (lg,lr); q cols j=0,1
  const float* gB = input + (size_t)b * IDF * QLN + q0 + wqp * 32 + lr;

  // prologue (FIFO per wave): A0 x4, B0 x16, A1 x4
  gload16(gAh, lds + dAh);
  gload16(gAh + 16 * IDF, lds + dAh + 1024);
  gload16(gAl, lds + dAl);
  gload16(gAl + 16 * IDF, lds + dAl + 1024);
  float aB[2][8], bB[2][8];
#pragma unroll
  for (int j = 0; j < 2; ++j)
#pragma unroll
    for (int e = 0; e < 8; ++e)
      aB[j][e] = gB[(size_t)(lg * 8 + e) * QLN + j * 16];
  gload16(gAh + 32, lds + 16384 + dAh);
  gload16(gAh + 16 * IDF + 32, lds + 16384 + dAh + 1024);
  gload16(gAl + 32, lds + 16384 + dAl);
  gload16(gAl + 16 * IDF + 32, lds + 16384 + dAl + 1024);

#define QK_WIN(CUROFF, BCUR, BNXT, IT, VMC)                                    \
  {                                                                            \
    asm volatile("s_waitcnt vmcnt(" #VMC ")" ::: "memory");                    \
    __builtin_amdgcn_sched_barrier(0);                                         \
    __builtin_amdgcn_s_barrier();                                              \
    __builtin_amdgcn_sched_barrier(0);                                         \
    if ((IT) + 1 < NT) {                                                       \
      _Pragma("unroll") for (int j = 0; j < 2; ++j)                            \
          _Pragma("unroll") for (int e = 0; e < 8; ++e)                        \
          BNXT[j][e] =                                                         \
              gB[(size_t)(((IT) + 1) * 32 + lg * 8 + e) * QLN + j * 16];       \
    }                                                                          \
    __builtin_amdgcn_sched_barrier(0);                                         \
    v8bf bh[2], bl[2];                                                         \
    _Pragma("unroll") for (int j = 0; j < 2; ++j)                              \
        _Pragma("unroll") for (int e = 0; e < 8; ++e) {                        \
      __bf16 h, l;                                                             \
      split2(BCUR[j][e], h, l);                                                \
      bh[j][e] = h;                                                            \
      bl[j][e] = l;                                                            \
    }                                                                          \
    const __bf16* Ab = (const __bf16*)(lds + (CUROFF));                        \
    __builtin_amdgcn_s_setprio(1);                                             \
    _Pragma("unroll") for (int fr = 0; fr < 4; ++fr) {                         \
      const int r = sh2 * 64 + fr * 16 + lr;                                   \
      const int pp = (lg ^ ((r >> 1) & 3)) * 8;                                \
      v8bf ah = *(const v8bf*)(Ab + r * 32 + pp);                              \
      v8bf al = *(const v8bf*)(Ab + 4096 + r * 32 + pp);                       \
      _Pragma("unroll") for (int j = 0; j < 2; ++j) {                          \
        acc[fr][j] = MFMA16(ah, bh[j], acc[fr][j], 0, 0, 0);                   \
        acc[fr][j] = MFMA16(ah, bl[j], acc[fr][j], 0, 0, 0);                   \
        acc[fr][j] = MFMA16(al, bh[j], acc[fr][j], 0, 0, 0);                   \
      }                                                                        \
    }                                                                          \
    __builtin_amdgcn_s_setprio(0);                                             \
    asm volatile("s_waitcnt lgkmcnt(0)" ::: "memory");                         \
    __builtin_amdgcn_s_barrier();                                              \
    if ((IT) + 2 < NT) {                                                       \
      gload16(gAh + (size_t)((IT) + 2) * 32, lds + (CUROFF) + dAh);            \
      gload16(gAh + 16 * IDF + (size_t)((IT) + 2) * 32,                        \
              lds + (CUROFF) + dAh + 1024);                                    \
      gload16(gAl + (size_t)((IT) + 2) * 32, lds + (CUROFF) + dAl);            \
      gload16(gAl + 16 * IDF + (size_t)((IT) + 2) * 32,                        \
              lds + (CUROFF) + dAl + 1024);                                    \
    }                                                                          \
  }

  for (int it2 = 0; it2 < 11; ++it2) {
    const int itE = it2 * 2;
    QK_WIN(0, aB, bB, itE, 4);
    QK_WIN(16384, bB, aB, itE + 1, 4);
  }
  QK_WIN(0, aB, bB, 22, 4);
  QK_WIN(16384, bB, aB, 23, 0);
#undef QK_WIN

  // softmax over s=128; lane covers q = q0 + (wqp*2+j)*16 + lr, s-half sh2
  float mx[2], sum[2];
#pragma unroll
  for (int j = 0; j < 2; ++j) {
    mx[j] = -3.0e38f;
#pragma unroll
    for (int fr = 0; fr < 4; ++fr)
#pragma unroll
      for (int r = 0; r < 4; ++r) {
        acc[fr][j][r] += msk[sh2 * 64 + fr * 16 + lg * 4 + r];
        mx[j] = fmaxf(mx[j], acc[fr][j][r]);
      }
    mx[j] = fmaxf(mx[j], __shfl_xor(mx[j], 16));
    mx[j] = fmaxf(mx[j], __shfl_xor(mx[j], 32));
    if (lg == 0) redm[sh2 * 64 + wqp * 32 + j * 16 + lr] = mx[j];
  }
  __syncthreads();
#pragma unroll
  for (int j = 0; j < 2; ++j) {
    const int qh = wqp * 32 + j * 16 + lr;
    mx[j] = fmaxf(redm[qh], redm[64 + qh]);
    sum[j] = 0.f;
#pragma unroll
    for (int fr = 0; fr < 4; ++fr)
#pragma unroll
      for (int r = 0; r < 4; ++r) {
        float e = __expf(acc[fr][j][r] - mx[j]);
        acc[fr][j][r] = e;
        sum[j] += e;
      }
    sum[j] += __shfl_xor(sum[j], 16);
    sum[j] += __shfl_xor(sum[j], 32);
    if (lg == 0) reds[sh2 * 64 + wqp * 32 + j * 16 + lr] = sum[j];
  }
  __syncthreads();
#pragma unroll
  for (int j = 0; j < 2; ++j) {
    const int qh = wqp * 32 + j * 16 + lr;
    const float inv = 1.0f / (reds[qh] + reds[64 + qh]);
    const int q = q0 + qh;
#pragma unroll
    for (int fr = 0; fr < 4; ++fr) {
      __bf16 hp[4];
#pragma unroll
      for (int r = 0; r < 4; ++r) {
        float p = acc[fr][j][r] * inv;
        attn_out[((size_t)b * SLN + sh2 * 64 + fr * 16 + lg * 4 + r) * QLN + q] =
            p;
        hp[r] = (__bf16)p;
      }
      const int g = (sh2 * 8 + fr * 2 + (lg >> 1)) ^ lr;
      *(v4bf*)(PLb + qh * 256 + g * 16 + (lg & 1) * 8) =
          (v4bf){hp[0], hp[1], hp[2], hp[3]};
    }
  }
  __syncthreads();

  // ---- PV: wave -> (qfp = (w&1)*2, islab = (w>>1)*384, 24 i-frags) ----
  const int qfp = (w & 1) * 2;
  const int islab = (w >> 1) * 384;
  v8bf pa0v[4], pa1v[4];
#pragma unroll
  for (int kt = 0; kt < 4; ++kt) {
    const int g0 = (kt * 4 + lg) ^ lr;
    pa0v[kt] = *(const v8bf*)(PLb + (qfp * 16 + lr) * 256 + g0 * 16);
    pa1v[kt] = *(const v8bf*)(PLb + ((qfp + 1) * 16 + lr) * 256 + g0 * 16);
  }
  const __bf16* pShv = Shv + ((size_t)b * IDF + islab + lr) * SLN + lg * 8;
  float* pWc = wc + ((size_t)b * IDF + islab + lr) * QLN + q0;
#pragma unroll 2
  for (int ifr = 0; ifr < 24; ++ifr) {
    v4f a0 = (v4f){0.f, 0.f, 0.f, 0.f};
    v4f a1 = (v4f){0.f, 0.f, 0.f, 0.f};
#pragma unroll
    for (int kt = 0; kt < 4; ++kt) {
      v8bf bb = *(const v8bf*)(pShv + (size_t)(ifr * 16) * SLN + kt * 32);
      a0 = MFMA16(pa0v[kt], bb, a0, 0, 0, 0);
      a1 = MFMA16(pa1v[kt], bb, a1, 0, 0, 0);
    }
    *(float4*)(pWc + (size_t)(ifr * 16) * QLN + qfp * 16 + lg * 4) =
        make_float4(a0[0], a0[1], a0[2], a0[3]);
    *(float4*)(pWc + (size_t)(ifr * 16) * QLN + (qfp + 1) * 16 + lg * 4) =
        make_float4(a1[0], a1[1], a1[2], a1[3]);
  }
}

// -----------------------------------------------------------------------------
extern "C" void kernel_launch(void* const* d_in, const int* in_sizes, int n_in,
                              void* d_out, int out_size, void* d_ws, size_t ws_size,
                              hipStream_t stream) {
  const float* input   = (const float*)d_in[0];
  const float* context = (const float*)d_in[1];
  const int*   mask    = (const int*)d_in[2];
  const float* w_conv  = (const float*)d_in[3];

  float* out      = (float*)d_out;
  float* wc       = out;
  float* attn_out = out + (size_t)NB * IDF * QLN;

  const size_t SE = (size_t)NB * SLN * IDF;  // 3,145,728
  const size_t WE = (size_t)IDF * IDF;       // 589,824
  __bf16* wsb = (__bf16*)d_ws;
  __bf16* STh = wsb;
  __bf16* STl = STh + SE;
  __bf16* Shv = STl + SE;
  __bf16* scr = (__bf16*)wc;  // scratch in output region (dead before PV)
  __bf16* cTh = scr;
  __bf16* cTl = cTh + SE;
  __bf16* Wh  = cTl + SE;
  __bf16* Wl  = Wh + WE;

  prep_k<<<960, 256, 0, stream>>>(w_conv, context, Wh, Wl, cTh, cTl);
  proj_k<<<dim3(24, NB), 256, 0, stream>>>(cTh, cTl, Wh, Wl, STh, STl, Shv);
  qkpv_k<<<512, 256, 0, stream>>>(input, STh, STl, Shv, mask, wc, attn_out);
}

// Round 20
// 85.698 us; speedup vs baseline: 2.2619x; 1.2715x over previous
//
#include <hip/hip_runtime.h>

#define NB  32
#define IDF 768
#define SLN 128
#define QLN 1024
#define NT  24   // IDF/32 k-tiles (even)

typedef _Float16 v8hf __attribute__((ext_vector_type(8)));
typedef _Float16 v4hf __attribute__((ext_vector_type(4)));
typedef float    v4f  __attribute__((ext_vector_type(4)));

#define MFMAH __builtin_amdgcn_mfma_f32_16x16x32_f16

__device__ __forceinline__ void gload16(const void* g, void* l) {
  __builtin_amdgcn_global_load_lds(
      (const __attribute__((address_space(1))) void*)g,
      (__attribute__((address_space(3))) void*)l, 16, 0, 0);
}

__device__ __forceinline__ void lbar() {
  asm volatile("s_waitcnt lgkmcnt(0)" ::: "memory");
  __builtin_amdgcn_sched_barrier(0);
  __builtin_amdgcn_s_barrier();
  __builtin_amdgcn_sched_barrier(0);
}

// -----------------------------------------------------------------------------
// K0 prep: blocks 0..575: W f32 -> Wf fp16; blocks 576..959: transpose ctx
// [b][c][s] f32 -> cTf [b][s][c] fp16.
// -----------------------------------------------------------------------------
__global__ __launch_bounds__(256) void prep_k(const float* __restrict__ W,
                                              const float* __restrict__ ctx,
                                              _Float16* __restrict__ Wf,
                                              _Float16* __restrict__ cTf) {
  const int bid = blockIdx.x, t = threadIdx.x;
  __shared__ float tl[64][133];
  if (bid < 576) {
    int idx = bid * 1024 + t * 4;
    float4 v = *(const float4*)(W + idx);
    v4hf h;
    h[0] = (_Float16)v.x;
    h[1] = (_Float16)v.y;
    h[2] = (_Float16)v.z;
    h[3] = (_Float16)v.w;
    *(v4hf*)(Wf + idx) = h;
    return;
  }
  const int cid = bid - 576;
  const int b = cid / 12, c0 = (cid % 12) * 64;
#pragma unroll
  for (int j = 0; j < 8; ++j) {
    int u = j * 256 + t;
    int c = u >> 5, s4 = (u & 31) * 4;
    *(float4*)&tl[c][s4] =
        *(const float4*)(ctx + ((size_t)b * IDF + c0 + c) * SLN + s4);
  }
  __syncthreads();
#pragma unroll
  for (int j = 0; j < 8; ++j) {
    int u = j * 256 + t;
    int s = u >> 4, c4 = (u & 15) * 4;
    v4hf h;
#pragma unroll
    for (int e = 0; e < 4; ++e) h[e] = (_Float16)tl[c4 + e][s];
    *(v4hf*)(cTf + ((size_t)b * SLN + s) * IDF + c0 + c4) = h;
  }
}

// -----------------------------------------------------------------------------
// K1 proj: D[s][o] = sum_c cT[s][c] * W[o][c], all fp16 inputs, fp32 acc.
// Tile 128s x 32o, grid (24,32), 4 waves (ws = w>>1 s-half, wq = w&1 o-16).
// A = cTf via reg-staged XOR-swizzled LDS (single tensor, 2 uint4/thread),
// 2-deep named prefetch; B = Wf frags 1-deep from L2. 4 MFMA/wave/window.
// Outputs STf [b][s][768], Shvf [b][o][s] (both fp16).
// -----------------------------------------------------------------------------
__global__ __launch_bounds__(256) void proj_k(const _Float16* __restrict__ cTf,
                                              const _Float16* __restrict__ Wf,
                                              _Float16* __restrict__ STf,
                                              _Float16* __restrict__ Shvf) {
  const int b = blockIdx.y, o0 = blockIdx.x * 32;
  const int t = threadIdx.x, w = t >> 6, lane = t & 63;
  const int lr = lane & 15, lg = lane >> 4;
  const int ws = w >> 1, wq = w & 1;
  __shared__ _Float16 AL[128][32];

  v4f acc[4];
#pragma unroll
  for (int fr = 0; fr < 4; ++fr) acc[fr] = (v4f){0.f, 0.f, 0.f, 0.f};

  const int ra = t >> 1, ca0 = (t & 1) * 2;
  const int swA = (ra >> 1) & 3;
  const int pa0 = (ca0 ^ swA) * 8, pa1 = ((ca0 + 1) ^ swA) * 8;
  const _Float16* pA = cTf + ((size_t)b * SLN + ra) * IDF + ca0 * 8;
  const size_t wOff = (size_t)(o0 + wq * 16 + lr) * IDF + lg * 8;

  uint4 aA0, aA1, bA0, bA1;
  v8hf bhc, bhn;
  aA0 = *(const uint4*)(pA);
  aA1 = *(const uint4*)(pA + 8);
  bA0 = *(const uint4*)(pA + 32);
  bA1 = *(const uint4*)(pA + 40);
  bhc = *(const v8hf*)(Wf + wOff);

#define PROJ_BODY(S0, S1, IT)                                                  \
  {                                                                            \
    lbar();                                                                    \
    *(uint4*)&AL[ra][pa0] = S0;                                                \
    *(uint4*)&AL[ra][pa1] = S1;                                                \
    if ((IT) + 2 < NT) {                                                       \
      S0 = *(const uint4*)(pA + ((IT) + 2) * 32);                              \
      S1 = *(const uint4*)(pA + ((IT) + 2) * 32 + 8);                          \
    }                                                                          \
    if ((IT) + 1 < NT) {                                                       \
      bhn = *(const v8hf*)(Wf + wOff + ((IT) + 1) * 32);                       \
    }                                                                          \
    lbar();                                                                    \
    _Pragma("unroll") for (int fr = 0; fr < 4; ++fr) {                         \
      const int r = ws * 64 + fr * 16 + lr;                                    \
      const int pp = (lg ^ ((r >> 1) & 3)) * 8;                                \
      v8hf ah = *(const v8hf*)&AL[r][pp];                                      \
      acc[fr] = MFMAH(ah, bhc, acc[fr], 0, 0, 0);                              \
    }                                                                          \
    bhc = bhn;                                                                 \
  }

  for (int it2 = 0; it2 < NT / 2; ++it2) {
    const int itE = it2 * 2;
    PROJ_BODY(aA0, aA1, itE);
    PROJ_BODY(bA0, bA1, itE + 1);
  }
#undef PROJ_BODY

  const int o = o0 + wq * 16 + lr;
#pragma unroll
  for (int fr = 0; fr < 4; ++fr) {
    v4hf hp;
#pragma unroll
    for (int r = 0; r < 4; ++r) {
      int s = ws * 64 + fr * 16 + lg * 4 + r;
      _Float16 h = (_Float16)acc[fr][r];
      STf[((size_t)b * SLN + s) * IDF + o] = h;
      hp[r] = h;
    }
    *(v4hf*)(Shvf + ((size_t)b * IDF + o) * SLN + ws * 64 + fr * 16 + lg * 4) =
        hp;
  }
}

// -----------------------------------------------------------------------------
// K2 qkpv (round-19 geometry, fp16): 256 threads, 4 waves (wqp = w&1 2 q-frags,
// sh2 = w>>1 s-half, acc[4][2], 8 MFMA/wave/window). A = STf via gload_lds
// (2 instrs/wave/window, XOR-presourced, linear LDS). B = input direct-global
// regs, 1 cvt each, prefetched 1 window ahead. FIFO vmcnt: steady 2, final 0.
// PL + PV in fp16 (P more accurate than old bf16). LDS 17.9 KB.
// -----------------------------------------------------------------------------
__global__ __launch_bounds__(256, 4) void qkpv_k(const float* __restrict__ input,
                                                 const _Float16* __restrict__ STf,
                                                 const _Float16* __restrict__ Shvf,
                                                 const int* __restrict__ mask,
                                                 float* __restrict__ wc,
                                                 float* __restrict__ attn_out) {
  const int bid = blockIdx.x;
  const int nid = (bid & 7) * 64 + (bid >> 3);  // XCD swizzle, 512 blocks
  const int b = nid >> 4, q0 = (nid & 15) * 64;
  const int t = threadIdx.x, w = t >> 6, lane = t & 63;
  const int lr = lane & 15, lg = lane >> 4;
  const int wqp = w & 1, sh2 = w >> 1;

  // LDS: buf0 @0 (8K: [128 s][32 k] fp16), buf1 @8192, msk @16384,
  // redm @16896, reds @17408. Total 17920 B. PL (16 KB) overlays buf0+buf1.
  __shared__ __align__(16) char lds[17920];
  float* const msk  = (float*)(lds + 16384);
  float* const redm = (float*)(lds + 16896);
  float* const reds = (float*)(lds + 17408);
  char* const PLb = lds;

  if (t < SLN) msk[t] = -10000.0f * (float)mask[b * SLN + t];

  v4f acc[4][2];
#pragma unroll
  for (int fr = 0; fr < 4; ++fr)
#pragma unroll
    for (int j = 0; j < 2; ++j) acc[fr][j] = (v4f){0.f, 0.f, 0.f, 0.f};

  // A staging: wave w stages rows [w*32, w*32+32) as two 16-row gloads.
  // XOR key (raA0>>1)&3 invariant under +16 rows.
  const int raA0 = w * 32 + (lane >> 2);
  const int cA   = (lane & 3) ^ ((raA0 >> 1) & 3);
  const _Float16* gA = STf + ((size_t)b * SLN + raA0) * IDF + cA * 8;
  const int dA = w * 2048;  // bytes within buffer (32 rows x 64B)

  // B direct-global: lane (lg,lr); q cols j=0,1
  const float* gB = input + (size_t)b * IDF * QLN + q0 + wqp * 32 + lr;

  // prologue (per-wave FIFO): A0 x2, B0 x16, A1 x2
  gload16(gA, lds + dA);
  gload16(gA + 16 * IDF, lds + dA + 1024);
  float aB[2][8], bB[2][8];
#pragma unroll
  for (int j = 0; j < 2; ++j)
#pragma unroll
    for (int e = 0; e < 8; ++e)
      aB[j][e] = gB[(size_t)(lg * 8 + e) * QLN + j * 16];
  gload16(gA + 32, lds + 8192 + dA);
  gload16(gA + 16 * IDF + 32, lds + 8192 + dA + 1024);

#define QK_WIN(CUROFF, BCUR, BNXT, IT, VMC)                                    \
  {                                                                            \
    asm volatile("s_waitcnt vmcnt(" #VMC ")" ::: "memory");                    \
    __builtin_amdgcn_sched_barrier(0);                                         \
    __builtin_amdgcn_s_barrier();                                              \
    __builtin_amdgcn_sched_barrier(0);                                         \
    if ((IT) + 1 < NT) {                                                       \
      _Pragma("unroll") for (int j = 0; j < 2; ++j)                            \
          _Pragma("unroll") for (int e = 0; e < 8; ++e)                        \
          BNXT[j][e] =                                                         \
              gB[(size_t)(((IT) + 1) * 32 + lg * 8 + e) * QLN + j * 16];       \
    }                                                                          \
    __builtin_amdgcn_sched_barrier(0);                                         \
    v8hf bh[2];                                                                \
    _Pragma("unroll") for (int j = 0; j < 2; ++j)                              \
        _Pragma("unroll") for (int e = 0; e < 8; ++e)                          \
        bh[j][e] = (_Float16)BCUR[j][e];                                       \
    const _Float16* Ab = (const _Float16*)(lds + (CUROFF));                    \
    __builtin_amdgcn_s_setprio(1);                                             \
    _Pragma("unroll") for (int fr = 0; fr < 4; ++fr) {                         \
      const int r = sh2 * 64 + fr * 16 + lr;                                   \
      const int pp = (lg ^ ((r >> 1) & 3)) * 8;                                \
      v8hf ah = *(const v8hf*)(Ab + r * 32 + pp);                              \
      _Pragma("unroll") for (int j = 0; j < 2; ++j) {                          \
        acc[fr][j] = MFMAH(ah, bh[j], acc[fr][j], 0, 0, 0);                    \
      }                                                                        \
    }                                                                          \
    __builtin_amdgcn_s_setprio(0);                                             \
    asm volatile("s_waitcnt lgkmcnt(0)" ::: "memory");                         \
    __builtin_amdgcn_s_barrier();                                              \
    if ((IT) + 2 < NT) {                                                       \
      gload16(gA + (size_t)((IT) + 2) * 32, lds + (CUROFF) + dA);              \
      gload16(gA + 16 * IDF + (size_t)((IT) + 2) * 32,                         \
              lds + (CUROFF) + dA + 1024);                                     \
    }                                                                          \
  }

  for (int it2 = 0; it2 < 11; ++it2) {
    const int itE = it2 * 2;
    QK_WIN(0, aB, bB, itE, 2);
    QK_WIN(8192, bB, aB, itE + 1, 2);
  }
  QK_WIN(0, aB, bB, 22, 2);
  QK_WIN(8192, bB, aB, 23, 0);
#undef QK_WIN

  // softmax over s=128; lane covers q = q0 + (wqp*2+j)*16 + lr, s-half sh2
  float mx[2], sum[2];
#pragma unroll
  for (int j = 0; j < 2; ++j) {
    mx[j] = -3.0e38f;
#pragma unroll
    for (int fr = 0; fr < 4; ++fr)
#pragma unroll
      for (int r = 0; r < 4; ++r) {
        acc[fr][j][r] += msk[sh2 * 64 + fr * 16 + lg * 4 + r];
        mx[j] = fmaxf(mx[j], acc[fr][j][r]);
      }
    mx[j] = fmaxf(mx[j], __shfl_xor(mx[j], 16));
    mx[j] = fmaxf(mx[j], __shfl_xor(mx[j], 32));
    if (lg == 0) redm[sh2 * 64 + wqp * 32 + j * 16 + lr] = mx[j];
  }
  __syncthreads();
#pragma unroll
  for (int j = 0; j < 2; ++j) {
    const int qh = wqp * 32 + j * 16 + lr;
    mx[j] = fmaxf(redm[qh], redm[64 + qh]);
    sum[j] = 0.f;
#pragma unroll
    for (int fr = 0; fr < 4; ++fr)
#pragma unroll
      for (int r = 0; r < 4; ++r) {
        float e = __expf(acc[fr][j][r] - mx[j]);
        acc[fr][j][r] = e;
        sum[j] += e;
      }
    sum[j] += __shfl_xor(sum[j], 16);
    sum[j] += __shfl_xor(sum[j], 32);
    if (lg == 0) reds[sh2 * 64 + wqp * 32 + j * 16 + lr] = sum[j];
  }
  __syncthreads();
#pragma unroll
  for (int j = 0; j < 2; ++j) {
    const int qh = wqp * 32 + j * 16 + lr;
    const float inv = 1.0f / (reds[qh] + reds[64 + qh]);
    const int q = q0 + qh;
#pragma unroll
    for (int fr = 0; fr < 4; ++fr) {
      v4hf hp;
#pragma unroll
      for (int r = 0; r < 4; ++r) {
        float p = acc[fr][j][r] * inv;
        attn_out[((size_t)b * SLN + sh2 * 64 + fr * 16 + lg * 4 + r) * QLN + q] =
            p;
        hp[r] = (_Float16)p;
      }
      const int g = (sh2 * 8 + fr * 2 + (lg >> 1)) ^ lr;
      *(v4hf*)(PLb + qh * 256 + g * 16 + (lg & 1) * 8) = hp;
    }
  }
  __syncthreads();

  // ---- PV: wave -> (qfp = (w&1)*2, islab = (w>>1)*384, 24 i-frags) ----
  const int qfp = (w & 1) * 2;
  const int islab = (w >> 1) * 384;
  v8hf pa0v[4], pa1v[4];
#pragma unroll
  for (int kt = 0; kt < 4; ++kt) {
    const int g0 = (kt * 4 + lg) ^ lr;
    pa0v[kt] = *(const v8hf*)(PLb + (qfp * 16 + lr) * 256 + g0 * 16);
    pa1v[kt] = *(const v8hf*)(PLb + ((qfp + 1) * 16 + lr) * 256 + g0 * 16);
  }
  const _Float16* pShv = Shvf + ((size_t)b * IDF + islab + lr) * SLN + lg * 8;
  float* pWc = wc + ((size_t)b * IDF + islab + lr) * QLN + q0;
#pragma unroll 2
  for (int ifr = 0; ifr < 24; ++ifr) {
    v4f a0 = (v4f){0.f, 0.f, 0.f, 0.f};
    v4f a1 = (v4f){0.f, 0.f, 0.f, 0.f};
#pragma unroll
    for (int kt = 0; kt < 4; ++kt) {
      v8hf bb = *(const v8hf*)(pShv + (size_t)(ifr * 16) * SLN + kt * 32);
      a0 = MFMAH(pa0v[kt], bb, a0, 0, 0, 0);
      a1 = MFMAH(pa1v[kt], bb, a1, 0, 0, 0);
    }
    *(float4*)(pWc + (size_t)(ifr * 16) * QLN + qfp * 16 + lg * 4) =
        make_float4(a0[0], a0[1], a0[2], a0[3]);
    *(float4*)(pWc + (size_t)(ifr * 16) * QLN + (qfp + 1) * 16 + lg * 4) =
        make_float4(a1[0], a1[1], a1[2], a1[3]);
  }
}

// -----------------------------------------------------------------------------
extern "C" void kernel_launch(void* const* d_in, const int* in_sizes, int n_in,
                              void* d_out, int out_size, void* d_ws, size_t ws_size,
                              hipStream_t stream) {
  const float* input   = (const float*)d_in[0];
  const float* context = (const float*)d_in[1];
  const int*   mask    = (const int*)d_in[2];
  const float* w_conv  = (const float*)d_in[3];

  float* out      = (float*)d_out;
  float* wc       = out;
  float* attn_out = out + (size_t)NB * IDF * QLN;

  // ws: STf | Shvf = 2*NB*SLN*IDF fp16 = 12,582,912 B (< 29.36 MB OK).
  // Scratch in wc output region (dead before PV): cTf | Wf.
  const size_t SE = (size_t)NB * SLN * IDF;  // 3,145,728
  const size_t WE = (size_t)IDF * IDF;       // 589,824
  _Float16* wsb = (_Float16*)d_ws;
  _Float16* STf  = wsb;
  _Float16* Shvf = STf + SE;
  _Float16* scr  = (_Float16*)wc;
  _Float16* cTf  = scr;
  _Float16* Wf   = cTf + SE;

  prep_k<<<960, 256, 0, stream>>>(w_conv, context, Wf, cTf);
  proj_k<<<dim3(24, NB), 256, 0, stream>>>(cTf, Wf, STf, Shvf);
  qkpv_k<<<512, 256, 0, stream>>>(input, STf, Shvf, mask, wc, attn_out);
}

// Round 21
// 83.034 us; speedup vs baseline: 2.3344x; 1.0321x over previous
//
#include <hip/hip_runtime.h>

#define NB  32
#define IDF 768
#define SLN 128
#define QLN 1024
#define NT  24    // IDF/32 (proj windows)
#define NT2 12    // IDF/64 (qkpv windows)

typedef _Float16 v8hf __attribute__((ext_vector_type(8)));
typedef _Float16 v4hf __attribute__((ext_vector_type(4)));
typedef float    v4f  __attribute__((ext_vector_type(4)));

#define MFMAH __builtin_amdgcn_mfma_f32_16x16x32_f16

__device__ __forceinline__ void gload16(const void* g, void* l) {
  __builtin_amdgcn_global_load_lds(
      (const __attribute__((address_space(1))) void*)g,
      (__attribute__((address_space(3))) void*)l, 16, 0, 0);
}

__device__ __forceinline__ void lbar() {
  asm volatile("s_waitcnt lgkmcnt(0)" ::: "memory");
  __builtin_amdgcn_sched_barrier(0);
  __builtin_amdgcn_s_barrier();
  __builtin_amdgcn_sched_barrier(0);
}

// -----------------------------------------------------------------------------
// K0 prep: blocks 0..575: W f32 -> Wf fp16; blocks 576..959: transpose ctx
// [b][c][s] f32 -> cTf [b][s][c] fp16.  (unchanged from round 20)
// -----------------------------------------------------------------------------
__global__ __launch_bounds__(256) void prep_k(const float* __restrict__ W,
                                              const float* __restrict__ ctx,
                                              _Float16* __restrict__ Wf,
                                              _Float16* __restrict__ cTf) {
  const int bid = blockIdx.x, t = threadIdx.x;
  __shared__ float tl[64][133];
  if (bid < 576) {
    int idx = bid * 1024 + t * 4;
    float4 v = *(const float4*)(W + idx);
    v4hf h;
    h[0] = (_Float16)v.x;
    h[1] = (_Float16)v.y;
    h[2] = (_Float16)v.z;
    h[3] = (_Float16)v.w;
    *(v4hf*)(Wf + idx) = h;
    return;
  }
  const int cid = bid - 576;
  const int b = cid / 12, c0 = (cid % 12) * 64;
#pragma unroll
  for (int j = 0; j < 8; ++j) {
    int u = j * 256 + t;
    int c = u >> 5, s4 = (u & 31) * 4;
    *(float4*)&tl[c][s4] =
        *(const float4*)(ctx + ((size_t)b * IDF + c0 + c) * SLN + s4);
  }
  __syncthreads();
#pragma unroll
  for (int j = 0; j < 8; ++j) {
    int u = j * 256 + t;
    int s = u >> 4, c4 = (u & 15) * 4;
    v4hf h;
#pragma unroll
    for (int e = 0; e < 4; ++e) h[e] = (_Float16)tl[c4 + e][s];
    *(v4hf*)(cTf + ((size_t)b * SLN + s) * IDF + c0 + c4) = h;
  }
}

// -----------------------------------------------------------------------------
// K1 proj: unchanged from round 20 (fp16, known-good).
// -----------------------------------------------------------------------------
__global__ __launch_bounds__(256) void proj_k(const _Float16* __restrict__ cTf,
                                              const _Float16* __restrict__ Wf,
                                              _Float16* __restrict__ STf,
                                              _Float16* __restrict__ Shvf) {
  const int b = blockIdx.y, o0 = blockIdx.x * 32;
  const int t = threadIdx.x, w = t >> 6, lane = t & 63;
  const int lr = lane & 15, lg = lane >> 4;
  const int ws = w >> 1, wq = w & 1;
  __shared__ _Float16 AL[128][32];

  v4f acc[4];
#pragma unroll
  for (int fr = 0; fr < 4; ++fr) acc[fr] = (v4f){0.f, 0.f, 0.f, 0.f};

  const int ra = t >> 1, ca0 = (t & 1) * 2;
  const int swA = (ra >> 1) & 3;
  const int pa0 = (ca0 ^ swA) * 8, pa1 = ((ca0 + 1) ^ swA) * 8;
  const _Float16* pA = cTf + ((size_t)b * SLN + ra) * IDF + ca0 * 8;
  const size_t wOff = (size_t)(o0 + wq * 16 + lr) * IDF + lg * 8;

  uint4 aA0, aA1, bA0, bA1;
  v8hf bhc, bhn;
  aA0 = *(const uint4*)(pA);
  aA1 = *(const uint4*)(pA + 8);
  bA0 = *(const uint4*)(pA + 32);
  bA1 = *(const uint4*)(pA + 40);
  bhc = *(const v8hf*)(Wf + wOff);

#define PROJ_BODY(S0, S1, IT)                                                  \
  {                                                                            \
    lbar();                                                                    \
    *(uint4*)&AL[ra][pa0] = S0;                                                \
    *(uint4*)&AL[ra][pa1] = S1;                                                \
    if ((IT) + 2 < NT) {                                                       \
      S0 = *(const uint4*)(pA + ((IT) + 2) * 32);                              \
      S1 = *(const uint4*)(pA + ((IT) + 2) * 32 + 8);                          \
    }                                                                          \
    if ((IT) + 1 < NT) {                                                       \
      bhn = *(const v8hf*)(Wf + wOff + ((IT) + 1) * 32);                       \
    }                                                                          \
    lbar();                                                                    \
    _Pragma("unroll") for (int fr = 0; fr < 4; ++fr) {                         \
      const int r = ws * 64 + fr * 16 + lr;                                    \
      const int pp = (lg ^ ((r >> 1) & 3)) * 8;                                \
      v8hf ah = *(const v8hf*)&AL[r][pp];                                      \
      acc[fr] = MFMAH(ah, bhc, acc[fr], 0, 0, 0);                              \
    }                                                                          \
    bhc = bhn;                                                                 \
  }

  for (int it2 = 0; it2 < NT / 2; ++it2) {
    const int itE = it2 * 2;
    PROJ_BODY(aA0, aA1, itE);
    PROJ_BODY(bA0, bA1, itE + 1);
  }
#undef PROJ_BODY

  const int o = o0 + wq * 16 + lr;
#pragma unroll
  for (int fr = 0; fr < 4; ++fr) {
    v4hf hp;
#pragma unroll
    for (int r = 0; r < 4; ++r) {
      int s = ws * 64 + fr * 16 + lg * 4 + r;
      _Float16 h = (_Float16)acc[fr][r];
      STf[((size_t)b * SLN + s) * IDF + o] = h;
      hp[r] = h;
    }
    *(v4hf*)(Shvf + ((size_t)b * IDF + o) * SLN + ws * 64 + fr * 16 + lg * 4) =
        hp;
  }
}

// -----------------------------------------------------------------------------
// K2 qkpv: BK=64 -> 12 windows, 16 MFMA/wave/window. 256 thr, 4 waves
// (wqp = w&1 2 q-frags, sh2 = w>>1 s-half). A buffer [128 r][64 k] fp16 16KB,
// chunk-XOR swizzle c' = c ^ (r&7) (read 2-way free); gload linear dest +
// inverse-swizzled source, 4 gload16/wave/window. B = input direct-global
// 32 f32 regs, prefetched 1 window ahead (named sets). FIFO vmcnt: steady 4
// (A(t+2) in flight), final 0. k-ascending per-acc order == round 20 ->
// bit-identical outputs. LDS 33.5 KB; PL (16 KB) overlays buf0.
// -----------------------------------------------------------------------------
__global__ __launch_bounds__(256, 4) void qkpv_k(const float* __restrict__ input,
                                                 const _Float16* __restrict__ STf,
                                                 const _Float16* __restrict__ Shvf,
                                                 const int* __restrict__ mask,
                                                 float* __restrict__ wc,
                                                 float* __restrict__ attn_out) {
  const int bid = blockIdx.x;
  const int nid = (bid & 7) * 64 + (bid >> 3);  // XCD swizzle, 512 blocks
  const int b = nid >> 4, q0 = (nid & 15) * 64;
  const int t = threadIdx.x, w = t >> 6, lane = t & 63;
  const int lr = lane & 15, lg = lane >> 4;
  const int wqp = w & 1, sh2 = w >> 1;

  // LDS: buf0 @0 (16K: [128 r][64 k] fp16, swizzled chunks), buf1 @16384,
  // msk @32768, redm @33280, reds @33792. Total 34304 B.
  __shared__ __align__(16) char lds[34304];
  float* const msk  = (float*)(lds + 32768);
  float* const redm = (float*)(lds + 33280);
  float* const reds = (float*)(lds + 33792);
  char* const PLb = lds;  // P tile (16 KB) overlays buf0 after QK

  if (t < SLN) msk[t] = -10000.0f * (float)mask[b * SLN + t];

  v4f acc[4][2];
#pragma unroll
  for (int fr = 0; fr < 4; ++fr)
#pragma unroll
    for (int j = 0; j < 2; ++j) acc[fr][j] = (v4f){0.f, 0.f, 0.f, 0.f};

  // A staging: wave w stages rows [w*32, w*32+32) x 64 k as 4 gloads.
  // gload g, lane l -> LDS row rA = g*8 + (l>>3), chunk c' = l&7 (linear);
  // global source chunk c = c' ^ (rA & 7)  (inverse swizzle).
  const int rA = (lane >> 3);              // + g*8 added per gload
  const int cpA = lane & 7;
  // per-gload global pointers (row w*32 + g*8 + rA, chunk cpA ^ ((row)&7))
  const _Float16* gA[4];
#pragma unroll
  for (int g = 0; g < 4; ++g) {
    const int row = w * 32 + g * 8 + rA;
    const int c = cpA ^ (row & 7);
    gA[g] = STf + ((size_t)b * SLN + row) * IDF + c * 8;
  }
  const int dA = w * 4096;  // bytes: 32 rows x 128 B

  // B direct-global: lane (lg,lr); q cols j=0,1; k-step kk=0,1
  const float* gB = input + (size_t)b * IDF * QLN + q0 + wqp * 32 + lr;
  // element (window IT, kk, j, e): gB[(IT*64 + kk*32 + lg*8 + e)*QLN + j*16]

  // prologue (per-wave FIFO): A(0) x4, B(0) x32, A(1) x4
#pragma unroll
  for (int g = 0; g < 4; ++g) gload16(gA[g], lds + dA + g * 1024);
  float aB[2][2][8], bB[2][2][8];
#pragma unroll
  for (int kk = 0; kk < 2; ++kk)
#pragma unroll
    for (int j = 0; j < 2; ++j)
#pragma unroll
      for (int e = 0; e < 8; ++e)
        aB[kk][j][e] = gB[(size_t)(kk * 32 + lg * 8 + e) * QLN + j * 16];
#pragma unroll
  for (int g = 0; g < 4; ++g) gload16(gA[g] + 64, lds + 16384 + dA + g * 1024);

#define QK_WIN(CUROFF, BCUR, BNXT, IT, VMC)                                    \
  {                                                                            \
    asm volatile("s_waitcnt vmcnt(" #VMC ")" ::: "memory");                    \
    __builtin_amdgcn_sched_barrier(0);                                         \
    __builtin_amdgcn_s_barrier();                                              \
    __builtin_amdgcn_sched_barrier(0);                                         \
    if ((IT) + 1 < NT2) {                                                      \
      _Pragma("unroll") for (int kk = 0; kk < 2; ++kk)                         \
          _Pragma("unroll") for (int j = 0; j < 2; ++j)                        \
          _Pragma("unroll") for (int e = 0; e < 8; ++e)                        \
          BNXT[kk][j][e] =                                                     \
              gB[(size_t)(((IT) + 1) * 64 + kk * 32 + lg * 8 + e) * QLN +      \
                 j * 16];                                                      \
    }                                                                          \
    __builtin_amdgcn_sched_barrier(0);                                         \
    v8hf bh[2][2];                                                             \
    _Pragma("unroll") for (int kk = 0; kk < 2; ++kk)                           \
        _Pragma("unroll") for (int j = 0; j < 2; ++j)                          \
        _Pragma("unroll") for (int e = 0; e < 8; ++e)                          \
        bh[kk][j][e] = (_Float16)BCUR[kk][j][e];                               \
    const char* Ab = lds + (CUROFF);                                           \
    __builtin_amdgcn_s_setprio(1);                                             \
    _Pragma("unroll") for (int fr = 0; fr < 4; ++fr) {                         \
      const int r = sh2 * 64 + fr * 16 + lr;                                   \
      _Pragma("unroll") for (int kk = 0; kk < 2; ++kk) {                       \
        const int cc = (kk * 4 + lg) ^ (r & 7);                                \
        v8hf ah = *(const v8hf*)(Ab + r * 128 + cc * 16);                      \
        _Pragma("unroll") for (int j = 0; j < 2; ++j) {                        \
          acc[fr][j] = MFMAH(ah, bh[kk][j], acc[fr][j], 0, 0, 0);              \
        }                                                                      \
      }                                                                        \
    }                                                                          \
    __builtin_amdgcn_s_setprio(0);                                             \
    asm volatile("s_waitcnt lgkmcnt(0)" ::: "memory");                         \
    __builtin_amdgcn_s_barrier();                                              \
    if ((IT) + 2 < NT2) {                                                      \
      _Pragma("unroll") for (int g = 0; g < 4; ++g)                            \
          gload16(gA[g] + (size_t)((IT) + 2) * 64,                             \
                  lds + (CUROFF) + dA + g * 1024);                             \
    }                                                                          \
  }

  for (int it2 = 0; it2 < 5; ++it2) {
    const int itE = it2 * 2;
    QK_WIN(0, aB, bB, itE, 4);
    QK_WIN(16384, bB, aB, itE + 1, 4);
  }
  QK_WIN(0, aB, bB, 10, 4);
  QK_WIN(16384, bB, aB, 11, 0);
#undef QK_WIN

  // softmax over s=128; lane covers q = q0 + (wqp*2+j)*16 + lr, s-half sh2
  float mx[2], sum[2];
#pragma unroll
  for (int j = 0; j < 2; ++j) {
    mx[j] = -3.0e38f;
#pragma unroll
    for (int fr = 0; fr < 4; ++fr)
#pragma unroll
      for (int r = 0; r < 4; ++r) {
        acc[fr][j][r] += msk[sh2 * 64 + fr * 16 + lg * 4 + r];
        mx[j] = fmaxf(mx[j], acc[fr][j][r]);
      }
    mx[j] = fmaxf(mx[j], __shfl_xor(mx[j], 16));
    mx[j] = fmaxf(mx[j], __shfl_xor(mx[j], 32));
    if (lg == 0) redm[sh2 * 64 + wqp * 32 + j * 16 + lr] = mx[j];
  }
  __syncthreads();
#pragma unroll
  for (int j = 0; j < 2; ++j) {
    const int qh = wqp * 32 + j * 16 + lr;
    mx[j] = fmaxf(redm[qh], redm[64 + qh]);
    sum[j] = 0.f;
#pragma unroll
    for (int fr = 0; fr < 4; ++fr)
#pragma unroll
      for (int r = 0; r < 4; ++r) {
        float e = __expf(acc[fr][j][r] - mx[j]);
        acc[fr][j][r] = e;
        sum[j] += e;
      }
    sum[j] += __shfl_xor(sum[j], 16);
    sum[j] += __shfl_xor(sum[j], 32);
    if (lg == 0) reds[sh2 * 64 + wqp * 32 + j * 16 + lr] = sum[j];
  }
  __syncthreads();
#pragma unroll
  for (int j = 0; j < 2; ++j) {
    const int qh = wqp * 32 + j * 16 + lr;
    const float inv = 1.0f / (reds[qh] + reds[64 + qh]);
    const int q = q0 + qh;
#pragma unroll
    for (int fr = 0; fr < 4; ++fr) {
      v4hf hp;
#pragma unroll
      for (int r = 0; r < 4; ++r) {
        float p = acc[fr][j][r] * inv;
        attn_out[((size_t)b * SLN + sh2 * 64 + fr * 16 + lg * 4 + r) * QLN + q] =
            p;
        hp[r] = (_Float16)p;
      }
      const int g = (sh2 * 8 + fr * 2 + (lg >> 1)) ^ lr;
      *(v4hf*)(PLb + qh * 256 + g * 16 + (lg & 1) * 8) = hp;
    }
  }
  __syncthreads();

  // ---- PV: wave -> (qfp = (w&1)*2, islab = (w>>1)*384, 24 i-frags) ----
  const int qfp = (w & 1) * 2;
  const int islab = (w >> 1) * 384;
  v8hf pa0v[4], pa1v[4];
#pragma unroll
  for (int kt = 0; kt < 4; ++kt) {
    const int g0 = (kt * 4 + lg) ^ lr;
    pa0v[kt] = *(const v8hf*)(PLb + (qfp * 16 + lr) * 256 + g0 * 16);
    pa1v[kt] = *(const v8hf*)(PLb + ((qfp + 1) * 16 + lr) * 256 + g0 * 16);
  }
  const _Float16* pShv = Shvf + ((size_t)b * IDF + islab + lr) * SLN + lg * 8;
  float* pWc = wc + ((size_t)b * IDF + islab + lr) * QLN + q0;
#pragma unroll 2
  for (int ifr = 0; ifr < 24; ++ifr) {
    v4f a0 = (v4f){0.f, 0.f, 0.f, 0.f};
    v4f a1 = (v4f){0.f, 0.f, 0.f, 0.f};
#pragma unroll
    for (int kt = 0; kt < 4; ++kt) {
      v8hf bb = *(const v8hf*)(pShv + (size_t)(ifr * 16) * SLN + kt * 32);
      a0 = MFMAH(pa0v[kt], bb, a0, 0, 0, 0);
      a1 = MFMAH(pa1v[kt], bb, a1, 0, 0, 0);
    }
    *(float4*)(pWc + (size_t)(ifr * 16) * QLN + qfp * 16 + lg * 4) =
        make_float4(a0[0], a0[1], a0[2], a0[3]);
    *(float4*)(pWc + (size_t)(ifr * 16) * QLN + (qfp + 1) * 16 + lg * 4) =
        make_float4(a1[0], a1[1], a1[2], a1[3]);
  }
}

// -----------------------------------------------------------------------------
extern "C" void kernel_launch(void* const* d_in, const int* in_sizes, int n_in,
                              void* d_out, int out_size, void* d_ws, size_t ws_size,
                              hipStream_t stream) {
  const float* input   = (const float*)d_in[0];
  const float* context = (const float*)d_in[1];
  const int*   mask    = (const int*)d_in[2];
  const float* w_conv  = (const float*)d_in[3];

  float* out      = (float*)d_out;
  float* wc       = out;
  float* attn_out = out + (size_t)NB * IDF * QLN;

  // ws: STf | Shvf = 12,582,912 B (< 29.36 MB OK).
  // Scratch in wc output region (dead before PV): cTf | Wf.
  const size_t SE = (size_t)NB * SLN * IDF;  // 3,145,728
  _Float16* wsb = (_Float16*)d_ws;
  _Float16* STf  = wsb;
  _Float16* Shvf = STf + SE;
  _Float16* scr  = (_Float16*)wc;
  _Float16* cTf  = scr;
  _Float16* Wf   = cTf + SE;

  prep_k<<<960, 256, 0, stream>>>(w_conv, context, Wf, cTf);
  proj_k<<<dim3(24, NB), 256, 0, stream>>>(cTf, Wf, STf, Shvf);
  qkpv_k<<<512, 256, 0, stream>>>(input, STf, Shvf, mask, wc, attn_out);
}

// Round 22
// 81.164 us; speedup vs baseline: 2.3882x; 1.0230x over previous
//
#include <hip/hip_runtime.h>

#define NB  32
#define IDF 768
#define SLN 128
#define QLN 1024
#define NT  24    // IDF/32 (proj windows)
#define NT2 12    // IDF/64 (qkpv windows)

typedef _Float16 v8hf __attribute__((ext_vector_type(8)));
typedef _Float16 v4hf __attribute__((ext_vector_type(4)));
typedef float    v4f  __attribute__((ext_vector_type(4)));

#define MFMAH __builtin_amdgcn_mfma_f32_16x16x32_f16

__device__ __forceinline__ void gload16(const void* g, void* l) {
  __builtin_amdgcn_global_load_lds(
      (const __attribute__((address_space(1))) void*)g,
      (__attribute__((address_space(3))) void*)l, 16, 0, 0);
}

__device__ __forceinline__ void lbar() {
  asm volatile("s_waitcnt lgkmcnt(0)" ::: "memory");
  __builtin_amdgcn_sched_barrier(0);
  __builtin_amdgcn_s_barrier();
  __builtin_amdgcn_sched_barrier(0);
}

// -----------------------------------------------------------------------------
// K0 prep: blocks 0..575: W f32 -> Wf fp16; blocks 576..959: transpose ctx
// [b][c][s] f32 -> cTf [b][s][c] fp16.  (unchanged)
// -----------------------------------------------------------------------------
__global__ __launch_bounds__(256) void prep_k(const float* __restrict__ W,
                                              const float* __restrict__ ctx,
                                              _Float16* __restrict__ Wf,
                                              _Float16* __restrict__ cTf) {
  const int bid = blockIdx.x, t = threadIdx.x;
  __shared__ float tl[64][133];
  if (bid < 576) {
    int idx = bid * 1024 + t * 4;
    float4 v = *(const float4*)(W + idx);
    v4hf h;
    h[0] = (_Float16)v.x;
    h[1] = (_Float16)v.y;
    h[2] = (_Float16)v.z;
    h[3] = (_Float16)v.w;
    *(v4hf*)(Wf + idx) = h;
    return;
  }
  const int cid = bid - 576;
  const int b = cid / 12, c0 = (cid % 12) * 64;
#pragma unroll
  for (int j = 0; j < 8; ++j) {
    int u = j * 256 + t;
    int c = u >> 5, s4 = (u & 31) * 4;
    *(float4*)&tl[c][s4] =
        *(const float4*)(ctx + ((size_t)b * IDF + c0 + c) * SLN + s4);
  }
  __syncthreads();
#pragma unroll
  for (int j = 0; j < 8; ++j) {
    int u = j * 256 + t;
    int s = u >> 4, c4 = (u & 15) * 4;
    v4hf h;
#pragma unroll
    for (int e = 0; e < 4; ++e) h[e] = (_Float16)tl[c4 + e][s];
    *(v4hf*)(cTf + ((size_t)b * SLN + s) * IDF + c0 + c4) = h;
  }
}

// -----------------------------------------------------------------------------
// K1 proj: unchanged (fp16, known-good).
// -----------------------------------------------------------------------------
__global__ __launch_bounds__(256) void proj_k(const _Float16* __restrict__ cTf,
                                              const _Float16* __restrict__ Wf,
                                              _Float16* __restrict__ STf,
                                              _Float16* __restrict__ Shvf) {
  const int b = blockIdx.y, o0 = blockIdx.x * 32;
  const int t = threadIdx.x, w = t >> 6, lane = t & 63;
  const int lr = lane & 15, lg = lane >> 4;
  const int ws = w >> 1, wq = w & 1;
  __shared__ _Float16 AL[128][32];

  v4f acc[4];
#pragma unroll
  for (int fr = 0; fr < 4; ++fr) acc[fr] = (v4f){0.f, 0.f, 0.f, 0.f};

  const int ra = t >> 1, ca0 = (t & 1) * 2;
  const int swA = (ra >> 1) & 3;
  const int pa0 = (ca0 ^ swA) * 8, pa1 = ((ca0 + 1) ^ swA) * 8;
  const _Float16* pA = cTf + ((size_t)b * SLN + ra) * IDF + ca0 * 8;
  const size_t wOff = (size_t)(o0 + wq * 16 + lr) * IDF + lg * 8;

  uint4 aA0, aA1, bA0, bA1;
  v8hf bhc, bhn;
  aA0 = *(const uint4*)(pA);
  aA1 = *(const uint4*)(pA + 8);
  bA0 = *(const uint4*)(pA + 32);
  bA1 = *(const uint4*)(pA + 40);
  bhc = *(const v8hf*)(Wf + wOff);

#define PROJ_BODY(S0, S1, IT)                                                  \
  {                                                                            \
    lbar();                                                                    \
    *(uint4*)&AL[ra][pa0] = S0;                                                \
    *(uint4*)&AL[ra][pa1] = S1;                                                \
    if ((IT) + 2 < NT) {                                                       \
      S0 = *(const uint4*)(pA + ((IT) + 2) * 32);                              \
      S1 = *(const uint4*)(pA + ((IT) + 2) * 32 + 8);                          \
    }                                                                          \
    if ((IT) + 1 < NT) {                                                       \
      bhn = *(const v8hf*)(Wf + wOff + ((IT) + 1) * 32);                       \
    }                                                                          \
    lbar();                                                                    \
    _Pragma("unroll") for (int fr = 0; fr < 4; ++fr) {                         \
      const int r = ws * 64 + fr * 16 + lr;                                    \
      const int pp = (lg ^ ((r >> 1) & 3)) * 8;                                \
      v8hf ah = *(const v8hf*)&AL[r][pp];                                      \
      acc[fr] = MFMAH(ah, bhc, acc[fr], 0, 0, 0);                              \
    }                                                                          \
    bhc = bhn;                                                                 \
  }

  for (int it2 = 0; it2 < NT / 2; ++it2) {
    const int itE = it2 * 2;
    PROJ_BODY(aA0, aA1, itE);
    PROJ_BODY(bA0, bA1, itE + 1);
  }
#undef PROJ_BODY

  const int o = o0 + wq * 16 + lr;
#pragma unroll
  for (int fr = 0; fr < 4; ++fr) {
    v4hf hp;
#pragma unroll
    for (int r = 0; r < 4; ++r) {
      int s = ws * 64 + fr * 16 + lg * 4 + r;
      _Float16 h = (_Float16)acc[fr][r];
      STf[((size_t)b * SLN + s) * IDF + o] = h;
      hp[r] = h;
    }
    *(v4hf*)(Shvf + ((size_t)b * IDF + o) * SLN + ws * 64 + fr * 16 + lg * 4) =
        hp;
  }
}

// -----------------------------------------------------------------------------
// K2 qkpv: BK=64, 12 windows, 16 MFMA/wave/window; 256 thr, 4 waves.
// B prefetch REGISTER DIET: f32 loads land in ONE transient tmpB (32 regs,
// window-local); MFMA runs on previously-cvt'd v8hf set (16 regs); cvt of
// tmpB -> next set placed AFTER the MFMA cluster (loads get the cluster to
// land). Peak ~105 VGPR -> no spill at 4 blocks/CU. A via gload_lds with
// chunk-XOR c' = c ^ (r&7) presourced. vmcnt entry 4 (A(t+1) in flight),
// final 0. Values bit-identical to round 21.
// -----------------------------------------------------------------------------
__global__ __launch_bounds__(256, 4) void qkpv_k(const float* __restrict__ input,
                                                 const _Float16* __restrict__ STf,
                                                 const _Float16* __restrict__ Shvf,
                                                 const int* __restrict__ mask,
                                                 float* __restrict__ wc,
                                                 float* __restrict__ attn_out) {
  const int bid = blockIdx.x;
  const int nid = (bid & 7) * 64 + (bid >> 3);  // XCD swizzle, 512 blocks
  const int b = nid >> 4, q0 = (nid & 15) * 64;
  const int t = threadIdx.x, w = t >> 6, lane = t & 63;
  const int lr = lane & 15, lg = lane >> 4;
  const int wqp = w & 1, sh2 = w >> 1;

  // LDS: buf0 @0 (16K [128 r][64 k] fp16, swizzled chunks), buf1 @16384,
  // msk @32768, redm @33280, reds @33792. Total 34304 B -> 4 blocks/CU.
  __shared__ __align__(16) char lds[34304];
  float* const msk  = (float*)(lds + 32768);
  float* const redm = (float*)(lds + 33280);
  float* const reds = (float*)(lds + 33792);
  char* const PLb = lds;  // P tile (16 KB) overlays buf0 after QK

  if (t < SLN) msk[t] = -10000.0f * (float)mask[b * SLN + t];

  v4f acc[4][2];
#pragma unroll
  for (int fr = 0; fr < 4; ++fr)
#pragma unroll
    for (int j = 0; j < 2; ++j) acc[fr][j] = (v4f){0.f, 0.f, 0.f, 0.f};

  // A staging: wave w stages rows [w*32, w*32+32) x 64 k as 4 gloads.
  // gload g, lane l -> LDS row g*8 + (l>>3), chunk c' = l&7 (linear dest);
  // global source chunk c = c' ^ (row & 7)  (inverse swizzle).
  const int rA = (lane >> 3);
  const int cpA = lane & 7;
  const _Float16* gA[4];
#pragma unroll
  for (int g = 0; g < 4; ++g) {
    const int row = w * 32 + g * 8 + rA;
    const int c = cpA ^ (row & 7);
    gA[g] = STf + ((size_t)b * SLN + row) * IDF + c * 8;
  }
  const int dA = w * 4096;  // bytes: 32 rows x 128 B

  // B direct-global: lane (lg,lr); q cols j=0,1; k-step kk=0,1
  const float* gB = input + (size_t)b * IDF * QLN + q0 + wqp * 32 + lr;

  // prologue: A(0) gloads; B(0) load+cvt (prologue-only drain); A(1) gloads
#pragma unroll
  for (int g = 0; g < 4; ++g) gload16(gA[g], lds + dA + g * 1024);
  v8hf aH[2][2], bH[2][2];
  float tmpB[2][2][8];
#pragma unroll
  for (int kk = 0; kk < 2; ++kk)
#pragma unroll
    for (int j = 0; j < 2; ++j)
#pragma unroll
      for (int e = 0; e < 8; ++e)
        tmpB[kk][j][e] = gB[(size_t)(kk * 32 + lg * 8 + e) * QLN + j * 16];
#pragma unroll
  for (int kk = 0; kk < 2; ++kk)
#pragma unroll
    for (int j = 0; j < 2; ++j)
#pragma unroll
      for (int e = 0; e < 8; ++e) aH[kk][j][e] = (_Float16)tmpB[kk][j][e];
#pragma unroll
  for (int g = 0; g < 4; ++g) gload16(gA[g] + 64, lds + 16384 + dA + g * 1024);

#define QK_WIN(CUROFF, BC, BN, IT, VMC)                                        \
  {                                                                            \
    asm volatile("s_waitcnt vmcnt(" #VMC ")" ::: "memory");                    \
    __builtin_amdgcn_sched_barrier(0);                                         \
    __builtin_amdgcn_s_barrier();                                              \
    __builtin_amdgcn_sched_barrier(0);                                         \
    if ((IT) + 1 < NT2) {                                                      \
      _Pragma("unroll") for (int kk = 0; kk < 2; ++kk)                         \
          _Pragma("unroll") for (int j = 0; j < 2; ++j)                        \
          _Pragma("unroll") for (int e = 0; e < 8; ++e)                        \
          tmpB[kk][j][e] =                                                     \
              gB[(size_t)(((IT) + 1) * 64 + kk * 32 + lg * 8 + e) * QLN +      \
                 j * 16];                                                      \
    }                                                                          \
    __builtin_amdgcn_sched_barrier(0);                                         \
    const char* Ab = lds + (CUROFF);                                           \
    __builtin_amdgcn_s_setprio(1);                                             \
    _Pragma("unroll") for (int fr = 0; fr < 4; ++fr) {                         \
      const int r = sh2 * 64 + fr * 16 + lr;                                   \
      _Pragma("unroll") for (int kk = 0; kk < 2; ++kk) {                       \
        const int cc = (kk * 4 + lg) ^ (r & 7);                                \
        v8hf ah = *(const v8hf*)(Ab + r * 128 + cc * 16);                      \
        _Pragma("unroll") for (int j = 0; j < 2; ++j) {                        \
          acc[fr][j] = MFMAH(ah, BC[kk][j], acc[fr][j], 0, 0, 0);              \
        }                                                                      \
      }                                                                        \
    }                                                                          \
    __builtin_amdgcn_s_setprio(0);                                             \
    __builtin_amdgcn_sched_barrier(0);                                         \
    if ((IT) + 1 < NT2) {                                                      \
      _Pragma("unroll") for (int kk = 0; kk < 2; ++kk)                         \
          _Pragma("unroll") for (int j = 0; j < 2; ++j)                        \
          _Pragma("unroll") for (int e = 0; e < 8; ++e)                        \
          BN[kk][j][e] = (_Float16)tmpB[kk][j][e];                             \
    }                                                                          \
    asm volatile("s_waitcnt lgkmcnt(0)" ::: "memory");                         \
    __builtin_amdgcn_s_barrier();                                              \
    if ((IT) + 2 < NT2) {                                                      \
      _Pragma("unroll") for (int g = 0; g < 4; ++g)                            \
          gload16(gA[g] + (size_t)((IT) + 2) * 64,                             \
                  lds + (CUROFF) + dA + g * 1024);                             \
    }                                                                          \
  }

  for (int it2 = 0; it2 < 5; ++it2) {
    const int itE = it2 * 2;
    QK_WIN(0, aH, bH, itE, 4);
    QK_WIN(16384, bH, aH, itE + 1, 4);
  }
  QK_WIN(0, aH, bH, 10, 4);
  QK_WIN(16384, bH, aH, 11, 0);
#undef QK_WIN

  // softmax over s=128; lane covers q = q0 + (wqp*2+j)*16 + lr, s-half sh2
  float mx[2], sum[2];
#pragma unroll
  for (int j = 0; j < 2; ++j) {
    mx[j] = -3.0e38f;
#pragma unroll
    for (int fr = 0; fr < 4; ++fr)
#pragma unroll
      for (int r = 0; r < 4; ++r) {
        acc[fr][j][r] += msk[sh2 * 64 + fr * 16 + lg * 4 + r];
        mx[j] = fmaxf(mx[j], acc[fr][j][r]);
      }
    mx[j] = fmaxf(mx[j], __shfl_xor(mx[j], 16));
    mx[j] = fmaxf(mx[j], __shfl_xor(mx[j], 32));
    if (lg == 0) redm[sh2 * 64 + wqp * 32 + j * 16 + lr] = mx[j];
  }
  __syncthreads();
#pragma unroll
  for (int j = 0; j < 2; ++j) {
    const int qh = wqp * 32 + j * 16 + lr;
    mx[j] = fmaxf(redm[qh], redm[64 + qh]);
    sum[j] = 0.f;
#pragma unroll
    for (int fr = 0; fr < 4; ++fr)
#pragma unroll
      for (int r = 0; r < 4; ++r) {
        float e = __expf(acc[fr][j][r] - mx[j]);
        acc[fr][j][r] = e;
        sum[j] += e;
      }
    sum[j] += __shfl_xor(sum[j], 16);
    sum[j] += __shfl_xor(sum[j], 32);
    if (lg == 0) reds[sh2 * 64 + wqp * 32 + j * 16 + lr] = sum[j];
  }
  __syncthreads();
#pragma unroll
  for (int j = 0; j < 2; ++j) {
    const int qh = wqp * 32 + j * 16 + lr;
    const float inv = 1.0f / (reds[qh] + reds[64 + qh]);
    const int q = q0 + qh;
#pragma unroll
    for (int fr = 0; fr < 4; ++fr) {
      v4hf hp;
#pragma unroll
      for (int r = 0; r < 4; ++r) {
        float p = acc[fr][j][r] * inv;
        attn_out[((size_t)b * SLN + sh2 * 64 + fr * 16 + lg * 4 + r) * QLN + q] =
            p;
        hp[r] = (_Float16)p;
      }
      const int g = (sh2 * 8 + fr * 2 + (lg >> 1)) ^ lr;
      *(v4hf*)(PLb + qh * 256 + g * 16 + (lg & 1) * 8) = hp;
    }
  }
  __syncthreads();

  // ---- PV: wave -> (qfp = (w&1)*2, islab = (w>>1)*384, 24 i-frags) ----
  const int qfp = (w & 1) * 2;
  const int islab = (w >> 1) * 384;
  v8hf pa0v[4], pa1v[4];
#pragma unroll
  for (int kt = 0; kt < 4; ++kt) {
    const int g0 = (kt * 4 + lg) ^ lr;
    pa0v[kt] = *(const v8hf*)(PLb + (qfp * 16 + lr) * 256 + g0 * 16);
    pa1v[kt] = *(const v8hf*)(PLb + ((qfp + 1) * 16 + lr) * 256 + g0 * 16);
  }
  const _Float16* pShv = Shvf + ((size_t)b * IDF + islab + lr) * SLN + lg * 8;
  float* pWc = wc + ((size_t)b * IDF + islab + lr) * QLN + q0;
#pragma unroll 2
  for (int ifr = 0; ifr < 24; ++ifr) {
    v4f a0 = (v4f){0.f, 0.f, 0.f, 0.f};
    v4f a1 = (v4f){0.f, 0.f, 0.f, 0.f};
#pragma unroll
    for (int kt = 0; kt < 4; ++kt) {
      v8hf bb = *(const v8hf*)(pShv + (size_t)(ifr * 16) * SLN + kt * 32);
      a0 = MFMAH(pa0v[kt], bb, a0, 0, 0, 0);
      a1 = MFMAH(pa1v[kt], bb, a1, 0, 0, 0);
    }
    *(float4*)(pWc + (size_t)(ifr * 16) * QLN + qfp * 16 + lg * 4) =
        make_float4(a0[0], a0[1], a0[2], a0[3]);
    *(float4*)(pWc + (size_t)(ifr * 16) * QLN + (qfp + 1) * 16 + lg * 4) =
        make_float4(a1[0], a1[1], a1[2], a1[3]);
  }
}

// -----------------------------------------------------------------------------
extern "C" void kernel_launch(void* const* d_in, const int* in_sizes, int n_in,
                              void* d_out, int out_size, void* d_ws, size_t ws_size,
                              hipStream_t stream) {
  const float* input   = (const float*)d_in[0];
  const float* context = (const float*)d_in[1];
  const int*   mask    = (const int*)d_in[2];
  const float* w_conv  = (const float*)d_in[3];

  float* out      = (float*)d_out;
  float* wc       = out;
  float* attn_out = out + (size_t)NB * IDF * QLN;

  // ws: STf | Shvf = 12,582,912 B (< 29.36 MB OK).
  // Scratch in wc output region (dead before PV): cTf | Wf.
  const size_t SE = (size_t)NB * SLN * IDF;  // 3,145,728
  _Float16* wsb = (_Float16*)d_ws;
  _Float16* STf  = wsb;
  _Float16* Shvf = STf + SE;
  _Float16* scr  = (_Float16*)wc;
  _Float16* cTf  = scr;
  _Float16* Wf   = cTf + SE;

  prep_k<<<960, 256, 0, stream>>>(w_conv, context, Wf, cTf);
  proj_k<<<dim3(24, NB), 256, 0, stream>>>(cTf, Wf, STf, Shvf);
  qkpv_k<<<512, 256, 0, stream>>>(input, STf, Shvf, mask, wc, attn_out);
}